// Round 1
// baseline (1175.395 us; speedup 1.0000x reference)
//
#include <hip/hip_runtime.h>

constexpr int N_NODES  = 50000;
constexpr int N_EDGES  = 400000;
constexpr int N_GRAPHS = 512;
constexpr int IN_DIM   = 768;
constexpr int HID      = 64;
constexpr float BN_EPS = 1e-5f;

__device__ __forceinline__ void fma4(float4& a, float s, const float4& b) {
  a.x = fmaf(s, b.x, a.x);
  a.y = fmaf(s, b.y, a.y);
  a.z = fmaf(s, b.z, a.z);
  a.w = fmaf(s, b.w, a.w);
}

// P[n, 64] = X[n, 768] @ W[768, 64]   (64-row tiles, K staged in 64-chunks)
__global__ __launch_bounds__(256) void gemm_in(const float* __restrict__ X,
                                               const float* __restrict__ W,
                                               float* __restrict__ P) {
  __shared__ float xs[64][68];   // +4 pad: keeps float4 alignment, kills bank conflicts
  __shared__ float ws[64][64];
  const int tid  = threadIdx.x;
  const int row0 = blockIdx.x * 64;
  const int tc   = tid & 15;
  const int tr   = tid >> 4;
  const int r0   = tr << 2;
  const int c0   = tc << 2;

  float4 acc[4] = {};   // 4 rows x 4 cols per thread

  for (int kt = 0; kt < IN_DIM; kt += 64) {
#pragma unroll
    for (int i = 0; i < 4; i++) {
      int r  = tr + 16 * i;
      int gr = row0 + r;
      gr = gr < N_NODES ? gr : N_NODES - 1;   // clamp load; store is guarded
      *(float4*)&xs[r][tc * 4] =
          *(const float4*)&X[(size_t)gr * IN_DIM + kt + tc * 4];
      *(float4*)&ws[r][tc * 4] =
          *(const float4*)&W[(size_t)(kt + r) * HID + tc * 4];
    }
    __syncthreads();
#pragma unroll
    for (int k = 0; k < 64; k += 4) {
      float4 a0 = *(const float4*)&xs[r0 + 0][k];
      float4 a1 = *(const float4*)&xs[r0 + 1][k];
      float4 a2 = *(const float4*)&xs[r0 + 2][k];
      float4 a3 = *(const float4*)&xs[r0 + 3][k];
      float4 b0 = *(const float4*)&ws[k + 0][c0];
      float4 b1 = *(const float4*)&ws[k + 1][c0];
      float4 b2 = *(const float4*)&ws[k + 2][c0];
      float4 b3 = *(const float4*)&ws[k + 3][c0];
      fma4(acc[0], a0.x, b0); fma4(acc[0], a0.y, b1); fma4(acc[0], a0.z, b2); fma4(acc[0], a0.w, b3);
      fma4(acc[1], a1.x, b0); fma4(acc[1], a1.y, b1); fma4(acc[1], a1.z, b2); fma4(acc[1], a1.w, b3);
      fma4(acc[2], a2.x, b0); fma4(acc[2], a2.y, b1); fma4(acc[2], a2.z, b2); fma4(acc[2], a2.w, b3);
      fma4(acc[3], a3.x, b0); fma4(acc[3], a3.y, b1); fma4(acc[3], a3.z, b2); fma4(acc[3], a3.w, b3);
    }
    __syncthreads();
  }
#pragma unroll
  for (int i = 0; i < 4; i++) {
    int gr = row0 + r0 + i;
    if (gr < N_NODES) *(float4*)&P[(size_t)gr * HID + c0] = acc[i];
  }
}

// AGG[dst] += P[src], 64 floats per edge; 16 threads/edge, float4 gather + 4 atomics
__global__ __launch_bounds__(256) void scatter_add(const int* __restrict__ src,
                                                   const int* __restrict__ dst,
                                                   const float* __restrict__ P,
                                                   float* __restrict__ AGG) {
  int t = blockIdx.x * 256 + threadIdx.x;
  int e = t >> 4;
  if (e >= N_EDGES) return;
  int c = (t & 15) << 2;
  int s = src[e];
  int d = dst[e];
  float4 v = *(const float4*)&P[(size_t)s * HID + c];
  float* o = &AGG[(size_t)d * HID + c];
  atomicAdd(o + 0, v.x);
  atomicAdd(o + 1, v.y);
  atomicAdd(o + 2, v.z);
  atomicAdd(o + 3, v.w);
}

// OUT[n,64] = [relu_out]( h @ W + bout ), where
//   h = has_bn ? relu((A + AGG + bin)*s + t)   (BN folded to scale/shift)
//     : A
__global__ __launch_bounds__(256) void mlp64(
    const float* __restrict__ A, const float* __restrict__ AGG,
    const float* __restrict__ bin, const float* __restrict__ g,
    const float* __restrict__ be, const float* __restrict__ rm,
    const float* __restrict__ rv, const float* __restrict__ W,
    const float* __restrict__ bout, float* __restrict__ OUT,
    int has_bn, int relu_out) {
  __shared__ float hs[64][68];
  __shared__ float ws[64][64];
  __shared__ float sS[64];
  __shared__ float sT[64];
  const int tid  = threadIdx.x;
  const int row0 = blockIdx.x * 64;
  const int tc   = tid & 15;
  const int tr   = tid >> 4;
  const int r0   = tr << 2;
  const int c0   = tc << 2;

  if (tid < 64) {
    if (has_bn) {
      float s = g[tid] * rsqrtf(rv[tid] + BN_EPS);
      sS[tid] = s;
      sT[tid] = (bin[tid] - rm[tid]) * s + be[tid];
    } else {
      sS[tid] = 1.0f;
      sT[tid] = 0.0f;
    }
  }
#pragma unroll
  for (int i = 0; i < 4; i++) {
    int k = tr + 16 * i;
    *(float4*)&ws[k][tc * 4] = *(const float4*)&W[(size_t)k * HID + tc * 4];
  }
  __syncthreads();   // sS/sT ready

  {
    float4 sv = *(const float4*)&sS[tc * 4];
    float4 tv = *(const float4*)&sT[tc * 4];
#pragma unroll
    for (int i = 0; i < 4; i++) {
      int r  = tr + 16 * i;
      int gr = row0 + r;
      gr = gr < N_NODES ? gr : N_NODES - 1;
      float4 v = *(const float4*)&A[(size_t)gr * HID + tc * 4];
      if (AGG) {
        float4 a2 = *(const float4*)&AGG[(size_t)gr * HID + tc * 4];
        v.x += a2.x; v.y += a2.y; v.z += a2.z; v.w += a2.w;
      }
      if (has_bn) {
        v.x = fmaxf(fmaf(v.x, sv.x, tv.x), 0.0f);
        v.y = fmaxf(fmaf(v.y, sv.y, tv.y), 0.0f);
        v.z = fmaxf(fmaf(v.z, sv.z, tv.z), 0.0f);
        v.w = fmaxf(fmaf(v.w, sv.w, tv.w), 0.0f);
      }
      *(float4*)&hs[r][tc * 4] = v;
    }
  }
  __syncthreads();

  float4 acc[4] = {};
#pragma unroll
  for (int k = 0; k < 64; k += 4) {
    float4 a0 = *(const float4*)&hs[r0 + 0][k];
    float4 a1 = *(const float4*)&hs[r0 + 1][k];
    float4 a2 = *(const float4*)&hs[r0 + 2][k];
    float4 a3 = *(const float4*)&hs[r0 + 3][k];
    float4 b0 = *(const float4*)&ws[k + 0][c0];
    float4 b1 = *(const float4*)&ws[k + 1][c0];
    float4 b2 = *(const float4*)&ws[k + 2][c0];
    float4 b3 = *(const float4*)&ws[k + 3][c0];
    fma4(acc[0], a0.x, b0); fma4(acc[0], a0.y, b1); fma4(acc[0], a0.z, b2); fma4(acc[0], a0.w, b3);
    fma4(acc[1], a1.x, b0); fma4(acc[1], a1.y, b1); fma4(acc[1], a1.z, b2); fma4(acc[1], a1.w, b3);
    fma4(acc[2], a2.x, b0); fma4(acc[2], a2.y, b1); fma4(acc[2], a2.z, b2); fma4(acc[2], a2.w, b3);
    fma4(acc[3], a3.x, b0); fma4(acc[3], a3.y, b1); fma4(acc[3], a3.z, b2); fma4(acc[3], a3.w, b3);
  }

  float4 bo = make_float4(0.f, 0.f, 0.f, 0.f);
  if (bout) bo = *(const float4*)&bout[c0];
#pragma unroll
  for (int i = 0; i < 4; i++) {
    int gr = row0 + r0 + i;
    if (gr < N_NODES) {
      float4 v = acc[i];
      v.x += bo.x; v.y += bo.y; v.z += bo.z; v.w += bo.w;
      if (relu_out) {
        v.x = fmaxf(v.x, 0.f); v.y = fmaxf(v.y, 0.f);
        v.z = fmaxf(v.z, 0.f); v.w = fmaxf(v.w, 0.f);
      }
      *(float4*)&OUT[(size_t)gr * HID + c0] = v;
    }
  }
}

__global__ __launch_bounds__(256) void init_out(float* __restrict__ out,
                                                const float* __restrict__ bl) {
  int i = blockIdx.x * 256 + threadIdx.x;
  if (i < N_GRAPHS * 2) out[i] = bl[i & 1];
}

// out[batch[n]] += [x1[n], x2[n]] @ wl    (one wave per node, wave-reduce, 2 atomics)
__global__ __launch_bounds__(256) void pool(const float* __restrict__ x1,
                                            const float* __restrict__ x2,
                                            const int* __restrict__ batch,
                                            const float* __restrict__ wl,
                                            float* __restrict__ out) {
  int gt   = blockIdx.x * 256 + threadIdx.x;
  int n    = gt >> 6;
  int lane = threadIdx.x & 63;
  if (n >= N_NODES) return;
  float a = x1[(size_t)n * HID + lane];
  float b = x2[(size_t)n * HID + lane];
  float p0 = a * wl[lane * 2 + 0] + b * wl[(64 + lane) * 2 + 0];
  float p1 = a * wl[lane * 2 + 1] + b * wl[(64 + lane) * 2 + 1];
#pragma unroll
  for (int off = 32; off > 0; off >>= 1) {
    p0 += __shfl_down(p0, off);
    p1 += __shfl_down(p1, off);
  }
  if (lane == 0) {
    int gr = batch[n];
    atomicAdd(&out[gr * 2 + 0], p0);
    atomicAdd(&out[gr * 2 + 1], p1);
  }
}

extern "C" void kernel_launch(void* const* d_in, const int* in_sizes, int n_in,
                              void* d_out, int out_size, void* d_ws, size_t ws_size,
                              hipStream_t stream) {
  const float* x   = (const float*)d_in[0];
  const int*   ei  = (const int*)d_in[1];
  const int*   bat = (const int*)d_in[2];
  const float* w1a = (const float*)d_in[3];
  const float* b1a = (const float*)d_in[4];
  const float* g1  = (const float*)d_in[5];
  const float* be1 = (const float*)d_in[6];
  const float* rm1 = (const float*)d_in[7];
  const float* rv1 = (const float*)d_in[8];
  const float* w1b = (const float*)d_in[9];
  const float* b1b = (const float*)d_in[10];
  const float* w2a = (const float*)d_in[11];
  const float* b2a = (const float*)d_in[12];
  const float* g2  = (const float*)d_in[13];
  const float* be2 = (const float*)d_in[14];
  const float* rm2 = (const float*)d_in[15];
  const float* rv2 = (const float*)d_in[16];
  const float* w2b = (const float*)d_in[17];
  const float* b2b = (const float*)d_in[18];
  const float* wl  = (const float*)d_in[19];
  const float* bl  = (const float*)d_in[20];
  float* out = (float*)d_out;

  const int* src = ei;
  const int* dst = ei + N_EDGES;

  const size_t BUF = (size_t)N_NODES * HID;
  float* bufA = (float*)d_ws;    // p1, then p2
  float* bufB = bufA + BUF;      // agg (zeroed before each scatter)
  float* bufC = bufB + BUF;      // x1
  float* bufD = bufC + BUF;      // x2

  const int GB = (N_NODES + 63) / 64;               // 782 row-tiles
  const int SB = (N_EDGES * 16 + 255) / 256;        // 25000 scatter blocks
  const int PB = (N_NODES * 64 + 255) / 256;        // 12500 pool blocks

  // Layer 1: p1 = x @ w1a  (projection BEFORE aggregation — linearity)
  gemm_in<<<GB, 256, 0, stream>>>(x, w1a, bufA);
  hipMemsetAsync(bufB, 0, BUF * sizeof(float), stream);
  scatter_add<<<SB, 256, 0, stream>>>(src, dst, bufA, bufB);
  // x1 = relu( relu(BN(p1 + agg + b1a)) @ w1b + b1b )
  mlp64<<<GB, 256, 0, stream>>>(bufA, bufB, b1a, g1, be1, rm1, rv1, w1b, b1b,
                                bufC, 1, 1);
  // Layer 2: p2 = x1 @ w2a
  mlp64<<<GB, 256, 0, stream>>>(bufC, nullptr, nullptr, nullptr, nullptr,
                                nullptr, nullptr, w2a, nullptr, bufA, 0, 0);
  hipMemsetAsync(bufB, 0, BUF * sizeof(float), stream);
  scatter_add<<<SB, 256, 0, stream>>>(src, dst, bufA, bufB);
  mlp64<<<GB, 256, 0, stream>>>(bufA, bufB, b2a, g2, be2, rm2, rv2, w2b, b2b,
                                bufD, 1, 1);
  // Pool: out[g] = sum_n [x1,x2] @ wl + bl
  init_out<<<(N_GRAPHS * 2 + 255) / 256, 256, 0, stream>>>(out, bl);
  pool<<<PB, 256, 0, stream>>>(bufC, bufD, bat, wl, out);
}

// Round 2
// 558.244 us; speedup vs baseline: 2.1055x; 2.1055x over previous
//
#include <hip/hip_runtime.h>

constexpr int N_NODES  = 50000;
constexpr int N_EDGES  = 400000;
constexpr int N_GRAPHS = 512;
constexpr int IN_DIM   = 768;
constexpr int HID      = 64;
constexpr float BN_EPS = 1e-5f;
constexpr int CAP      = 32;     // bucket capacity per node; Poisson(8) max ~26

__device__ __forceinline__ void fma4(float4& a, float s, const float4& b) {
  a.x = fmaf(s, b.x, a.x);
  a.y = fmaf(s, b.y, a.y);
  a.z = fmaf(s, b.z, a.z);
  a.w = fmaf(s, b.w, a.w);
}

// P[n, 64] = X[n, 768] @ W[768, 64]   (64-row tiles, K staged in 64-chunks)
__global__ __launch_bounds__(256) void gemm_in(const float* __restrict__ X,
                                               const float* __restrict__ W,
                                               float* __restrict__ P) {
  __shared__ float xs[64][68];
  __shared__ float ws[64][64];
  const int tid  = threadIdx.x;
  const int row0 = blockIdx.x * 64;
  const int tc   = tid & 15;
  const int tr   = tid >> 4;
  const int r0   = tr << 2;
  const int c0   = tc << 2;

  float4 acc[4] = {};

  for (int kt = 0; kt < IN_DIM; kt += 64) {
#pragma unroll
    for (int i = 0; i < 4; i++) {
      int r  = tr + 16 * i;
      int gr = row0 + r;
      gr = gr < N_NODES ? gr : N_NODES - 1;
      *(float4*)&xs[r][tc * 4] =
          *(const float4*)&X[(size_t)gr * IN_DIM + kt + tc * 4];
      *(float4*)&ws[r][tc * 4] =
          *(const float4*)&W[(size_t)(kt + r) * HID + tc * 4];
    }
    __syncthreads();
#pragma unroll
    for (int k = 0; k < 64; k += 4) {
      float4 a0 = *(const float4*)&xs[r0 + 0][k];
      float4 a1 = *(const float4*)&xs[r0 + 1][k];
      float4 a2 = *(const float4*)&xs[r0 + 2][k];
      float4 a3 = *(const float4*)&xs[r0 + 3][k];
      float4 b0 = *(const float4*)&ws[k + 0][c0];
      float4 b1 = *(const float4*)&ws[k + 1][c0];
      float4 b2 = *(const float4*)&ws[k + 2][c0];
      float4 b3 = *(const float4*)&ws[k + 3][c0];
      fma4(acc[0], a0.x, b0); fma4(acc[0], a0.y, b1); fma4(acc[0], a0.z, b2); fma4(acc[0], a0.w, b3);
      fma4(acc[1], a1.x, b0); fma4(acc[1], a1.y, b1); fma4(acc[1], a1.z, b2); fma4(acc[1], a1.w, b3);
      fma4(acc[2], a2.x, b0); fma4(acc[2], a2.y, b1); fma4(acc[2], a2.z, b2); fma4(acc[2], a2.w, b3);
      fma4(acc[3], a3.x, b0); fma4(acc[3], a3.y, b1); fma4(acc[3], a3.z, b2); fma4(acc[3], a3.w, b3);
    }
    __syncthreads();
  }
#pragma unroll
  for (int i = 0; i < 4; i++) {
    int gr = row0 + r0 + i;
    if (gr < N_NODES) *(float4*)&P[(size_t)gr * HID + c0] = acc[i];
  }
}

// ---- CSR-ish bucket build (once per launch, reused by both layers) ----
// cnt[d] counts in-edges; bucket[d*CAP+slot] = src. Overflow -> (src,dst) list.
__global__ __launch_bounds__(256) void build_buckets(const int* __restrict__ src,
                                                     const int* __restrict__ dst,
                                                     int* __restrict__ cnt,
                                                     int* __restrict__ bucket,
                                                     int* __restrict__ ovf_cnt,
                                                     int* __restrict__ ovf) {
  int e = blockIdx.x * 256 + threadIdx.x;
  if (e >= N_EDGES) return;
  int s = src[e];
  int d = dst[e];
  int slot = atomicAdd(&cnt[d], 1);
  if (slot < CAP) {
    bucket[d * CAP + slot] = s;
  } else {
    int o = atomicAdd(ovf_cnt, 1);
    ovf[2 * o + 0] = s;
    ovf[2 * o + 1] = d;
  }
}

// AGG[n][lane] = sum over bucket entries of P[src][lane].  One wave per node.
__global__ __launch_bounds__(256) void gather_agg(const int* __restrict__ cnt,
                                                  const int* __restrict__ bucket,
                                                  const float* __restrict__ P,
                                                  float* __restrict__ AGG) {
  int n = blockIdx.x * 4 + (threadIdx.x >> 6);
  n = __builtin_amdgcn_readfirstlane(n);   // wave-uniform -> scalar loads
  int lane = threadIdx.x & 63;
  if (n >= N_NODES) return;
  int c = cnt[n];
  c = c < CAP ? c : CAP;
  const int* b = &bucket[n * CAP];
  float acc = 0.0f;
  int i = 0;
  for (; i + 4 <= c; i += 4) {
    int s0 = b[i + 0], s1 = b[i + 1], s2 = b[i + 2], s3 = b[i + 3];
    float v0 = P[(size_t)s0 * HID + lane];
    float v1 = P[(size_t)s1 * HID + lane];
    float v2 = P[(size_t)s2 * HID + lane];
    float v3 = P[(size_t)s3 * HID + lane];
    acc += (v0 + v1) + (v2 + v3);
  }
  for (; i < c; i++) acc += P[(size_t)b[i] * HID + lane];
  AGG[(size_t)n * HID + lane] = acc;
}

// Fallback for overflow edges (normally zero): grid-stride, 16 thr/edge atomics
__global__ __launch_bounds__(256) void ovf_scatter(const int* __restrict__ ovf_cnt,
                                                   const int* __restrict__ ovf,
                                                   const float* __restrict__ P,
                                                   float* __restrict__ AGG) {
  int total = *ovf_cnt * 16;
  for (int t = blockIdx.x * 256 + threadIdx.x; t < total; t += gridDim.x * 256) {
    int e = t >> 4;
    int c = (t & 15) << 2;
    int s = ovf[2 * e + 0];
    int d = ovf[2 * e + 1];
    float4 v = *(const float4*)&P[(size_t)s * HID + c];
    float* o = &AGG[(size_t)d * HID + c];
    atomicAdd(o + 0, v.x);
    atomicAdd(o + 1, v.y);
    atomicAdd(o + 2, v.z);
    atomicAdd(o + 3, v.w);
  }
}

// OUT[n,64] = [relu_out]( h @ W + bout ), h = has_bn ? relu(BN(A+AGG+bin)) : A
__global__ __launch_bounds__(256) void mlp64(
    const float* __restrict__ A, const float* __restrict__ AGG,
    const float* __restrict__ bin, const float* __restrict__ g,
    const float* __restrict__ be, const float* __restrict__ rm,
    const float* __restrict__ rv, const float* __restrict__ W,
    const float* __restrict__ bout, float* __restrict__ OUT,
    int has_bn, int relu_out) {
  __shared__ float hs[64][68];
  __shared__ float ws[64][64];
  __shared__ float sS[64];
  __shared__ float sT[64];
  const int tid  = threadIdx.x;
  const int row0 = blockIdx.x * 64;
  const int tc   = tid & 15;
  const int tr   = tid >> 4;
  const int r0   = tr << 2;
  const int c0   = tc << 2;

  if (tid < 64) {
    if (has_bn) {
      float s = g[tid] * rsqrtf(rv[tid] + BN_EPS);
      sS[tid] = s;
      sT[tid] = (bin[tid] - rm[tid]) * s + be[tid];
    } else {
      sS[tid] = 1.0f;
      sT[tid] = 0.0f;
    }
  }
#pragma unroll
  for (int i = 0; i < 4; i++) {
    int k = tr + 16 * i;
    *(float4*)&ws[k][tc * 4] = *(const float4*)&W[(size_t)k * HID + tc * 4];
  }
  __syncthreads();

  {
    float4 sv = *(const float4*)&sS[tc * 4];
    float4 tv = *(const float4*)&sT[tc * 4];
#pragma unroll
    for (int i = 0; i < 4; i++) {
      int r  = tr + 16 * i;
      int gr = row0 + r;
      gr = gr < N_NODES ? gr : N_NODES - 1;
      float4 v = *(const float4*)&A[(size_t)gr * HID + tc * 4];
      if (AGG) {
        float4 a2 = *(const float4*)&AGG[(size_t)gr * HID + tc * 4];
        v.x += a2.x; v.y += a2.y; v.z += a2.z; v.w += a2.w;
      }
      if (has_bn) {
        v.x = fmaxf(fmaf(v.x, sv.x, tv.x), 0.0f);
        v.y = fmaxf(fmaf(v.y, sv.y, tv.y), 0.0f);
        v.z = fmaxf(fmaf(v.z, sv.z, tv.z), 0.0f);
        v.w = fmaxf(fmaf(v.w, sv.w, tv.w), 0.0f);
      }
      *(float4*)&hs[r][tc * 4] = v;
    }
  }
  __syncthreads();

  float4 acc[4] = {};
#pragma unroll
  for (int k = 0; k < 64; k += 4) {
    float4 a0 = *(const float4*)&hs[r0 + 0][k];
    float4 a1 = *(const float4*)&hs[r0 + 1][k];
    float4 a2 = *(const float4*)&hs[r0 + 2][k];
    float4 a3 = *(const float4*)&hs[r0 + 3][k];
    float4 b0 = *(const float4*)&ws[k + 0][c0];
    float4 b1 = *(const float4*)&ws[k + 1][c0];
    float4 b2 = *(const float4*)&ws[k + 2][c0];
    float4 b3 = *(const float4*)&ws[k + 3][c0];
    fma4(acc[0], a0.x, b0); fma4(acc[0], a0.y, b1); fma4(acc[0], a0.z, b2); fma4(acc[0], a0.w, b3);
    fma4(acc[1], a1.x, b0); fma4(acc[1], a1.y, b1); fma4(acc[1], a1.z, b2); fma4(acc[1], a1.w, b3);
    fma4(acc[2], a2.x, b0); fma4(acc[2], a2.y, b1); fma4(acc[2], a2.z, b2); fma4(acc[2], a2.w, b3);
    fma4(acc[3], a3.x, b0); fma4(acc[3], a3.y, b1); fma4(acc[3], a3.z, b2); fma4(acc[3], a3.w, b3);
  }

  float4 bo = make_float4(0.f, 0.f, 0.f, 0.f);
  if (bout) bo = *(const float4*)&bout[c0];
#pragma unroll
  for (int i = 0; i < 4; i++) {
    int gr = row0 + r0 + i;
    if (gr < N_NODES) {
      float4 v = acc[i];
      v.x += bo.x; v.y += bo.y; v.z += bo.z; v.w += bo.w;
      if (relu_out) {
        v.x = fmaxf(v.x, 0.f); v.y = fmaxf(v.y, 0.f);
        v.z = fmaxf(v.z, 0.f); v.w = fmaxf(v.w, 0.f);
      }
      *(float4*)&OUT[(size_t)gr * HID + c0] = v;
    }
  }
}

__global__ __launch_bounds__(256) void init_out(float* __restrict__ out,
                                                const float* __restrict__ bl) {
  int i = blockIdx.x * 256 + threadIdx.x;
  if (i < N_GRAPHS * 2) out[i] = bl[i & 1];
}

__global__ __launch_bounds__(256) void pool(const float* __restrict__ x1,
                                            const float* __restrict__ x2,
                                            const int* __restrict__ batch,
                                            const float* __restrict__ wl,
                                            float* __restrict__ out) {
  int gt   = blockIdx.x * 256 + threadIdx.x;
  int n    = gt >> 6;
  int lane = threadIdx.x & 63;
  if (n >= N_NODES) return;
  float a = x1[(size_t)n * HID + lane];
  float b = x2[(size_t)n * HID + lane];
  float p0 = a * wl[lane * 2 + 0] + b * wl[(64 + lane) * 2 + 0];
  float p1 = a * wl[lane * 2 + 1] + b * wl[(64 + lane) * 2 + 1];
#pragma unroll
  for (int off = 32; off > 0; off >>= 1) {
    p0 += __shfl_down(p0, off);
    p1 += __shfl_down(p1, off);
  }
  if (lane == 0) {
    int gr = batch[n];
    atomicAdd(&out[gr * 2 + 0], p0);
    atomicAdd(&out[gr * 2 + 1], p1);
  }
}

extern "C" void kernel_launch(void* const* d_in, const int* in_sizes, int n_in,
                              void* d_out, int out_size, void* d_ws, size_t ws_size,
                              hipStream_t stream) {
  const float* x   = (const float*)d_in[0];
  const int*   ei  = (const int*)d_in[1];
  const int*   bat = (const int*)d_in[2];
  const float* w1a = (const float*)d_in[3];
  const float* b1a = (const float*)d_in[4];
  const float* g1  = (const float*)d_in[5];
  const float* be1 = (const float*)d_in[6];
  const float* rm1 = (const float*)d_in[7];
  const float* rv1 = (const float*)d_in[8];
  const float* w1b = (const float*)d_in[9];
  const float* b1b = (const float*)d_in[10];
  const float* w2a = (const float*)d_in[11];
  const float* b2a = (const float*)d_in[12];
  const float* g2  = (const float*)d_in[13];
  const float* be2 = (const float*)d_in[14];
  const float* rm2 = (const float*)d_in[15];
  const float* rv2 = (const float*)d_in[16];
  const float* w2b = (const float*)d_in[17];
  const float* b2b = (const float*)d_in[18];
  const float* wl  = (const float*)d_in[19];
  const float* bl  = (const float*)d_in[20];
  float* out = (float*)d_out;

  const int* src = ei;
  const int* dst = ei + N_EDGES;

  const size_t BUF = (size_t)N_NODES * HID;
  float* bufA = (float*)d_ws;    // p1, then p2
  float* bufB = bufA + BUF;      // agg
  float* bufC = bufB + BUF;      // x1
  float* bufD = bufC + BUF;      // x2 — ALSO aliases CSR region (see below)

  // CSR region aliases bufD: buckets are dead before the final mlp64 writes x2.
  int* cnt     = (int*)bufD;                  // 50000 ints
  int* ovf_cnt = cnt + N_NODES;               // 1 int (zeroed with cnt)
  int* bucket  = (int*)bufD + 65536;          // 50000*CAP ints = 6.4 MB
  int* ovf     = bucket + N_NODES * CAP;      // up to 2*N_EDGES ints = 3.2 MB

  const int GB = (N_NODES + 63) / 64;         // 782 row-tiles
  const int BB = (N_EDGES + 255) / 256;       // 1563 build blocks
  const int AB = (N_NODES + 3) / 4;           // 12500 gather blocks (4 nodes/block)
  const int PB = (N_NODES * 64 + 255) / 256;  // 12500 pool blocks

  // Build destination buckets once (shared by both layers)
  hipMemsetAsync(cnt, 0, (N_NODES + 64) * sizeof(int), stream);
  build_buckets<<<BB, 256, 0, stream>>>(src, dst, cnt, bucket, ovf_cnt, ovf);

  // Layer 1: p1 = x @ w1a (projection BEFORE aggregation — linearity)
  gemm_in<<<GB, 256, 0, stream>>>(x, w1a, bufA);
  gather_agg<<<AB, 256, 0, stream>>>(cnt, bucket, bufA, bufB);
  ovf_scatter<<<64, 256, 0, stream>>>(ovf_cnt, ovf, bufA, bufB);
  mlp64<<<GB, 256, 0, stream>>>(bufA, bufB, b1a, g1, be1, rm1, rv1, w1b, b1b,
                                bufC, 1, 1);
  // Layer 2: p2 = x1 @ w2a
  mlp64<<<GB, 256, 0, stream>>>(bufC, nullptr, nullptr, nullptr, nullptr,
                                nullptr, nullptr, w2a, nullptr, bufA, 0, 0);
  gather_agg<<<AB, 256, 0, stream>>>(cnt, bucket, bufA, bufB);
  ovf_scatter<<<64, 256, 0, stream>>>(ovf_cnt, ovf, bufA, bufB);
  mlp64<<<GB, 256, 0, stream>>>(bufA, bufB, b2a, g2, be2, rm2, rv2, w2b, b2b,
                                bufD, 1, 1);   // overwrites CSR region — last use was above
  // Pool
  init_out<<<(N_GRAPHS * 2 + 255) / 256, 256, 0, stream>>>(out, bl);
  pool<<<PB, 256, 0, stream>>>(bufC, bufD, bat, wl, out);
}

// Round 3
// 520.439 us; speedup vs baseline: 2.2585x; 1.0726x over previous
//
#include <hip/hip_runtime.h>

constexpr int N_NODES  = 50000;
constexpr int N_EDGES  = 400000;
constexpr int N_GRAPHS = 512;
constexpr int IN_DIM   = 768;
constexpr int HID      = 64;
constexpr float BN_EPS = 1e-5f;
constexpr int CAP      = 64;   // max in-degree ~27 for this graph (Poisson 8); 64 is bulletproof

typedef __attribute__((ext_vector_type(8))) short bf16x8;
typedef __attribute__((ext_vector_type(4))) float f32x4;

__device__ __forceinline__ float bf2f(ushort u) {
  return __uint_as_float((unsigned int)u << 16);
}
__device__ __forceinline__ ushort f2bf(float f) {  // RNE
  unsigned int u = __float_as_uint(f);
  u = (u + 0x7fff + ((u >> 16) & 1)) >> 16;
  return (ushort)u;
}
__device__ __forceinline__ void fma4(float4& a, float s, const float4& b) {
  a.x = fmaf(s, b.x, a.x);
  a.y = fmaf(s, b.y, a.y);
  a.z = fmaf(s, b.z, a.z);
  a.w = fmaf(s, b.w, a.w);
}

// WT[c][k] = bf16(W[k][c])  — B^T layout for MFMA b-frag contiguous loads
__global__ __launch_bounds__(256) void convert_w(const float* __restrict__ W,
                                                 ushort* __restrict__ WT) {
  int i = blockIdx.x * 256 + threadIdx.x;
  if (i >= HID * IN_DIM) return;
  int c = i / IN_DIM, k = i - c * IN_DIM;
  WT[i] = f2bf(W[(size_t)k * HID + c]);
}

// P[n,64] = bf16( X[n,768] @ W[768,64] )  via 16x16x32 bf16 MFMA.
// 64-row tile/block, 4 waves = 4 row-groups of 16; XOR-swizzled LDS (16B chunks);
// global loads for tile k+1 issued before the MFMAs of tile k.
__global__ __launch_bounds__(256) void gemm_in_mfma(const float* __restrict__ X,
                                                    const ushort* __restrict__ WT,
                                                    ushort* __restrict__ P) {
  __shared__ ushort xs[64][64];   // [row][k], 16B chunks XOR-swizzled by row&7
  __shared__ ushort ws[64][64];   // [col][k], same swizzle
  const int tid  = threadIdx.x;
  const int row0 = blockIdx.x * 64;
  const int wave = tid >> 6;
  const int lane = tid & 63;
  const int quad = lane >> 4;
  const int l16  = lane & 15;

  const int srow = tid >> 2;         // staging row (X) / col (WT): 0..63
  const int sk   = (tid & 3) * 16;   // staging k offset: 0/16/32/48
  const int ch0  = ((sk >> 3) + 0) ^ (srow & 7);
  const int ch1  = ((sk >> 3) + 1) ^ (srow & 7);

  int gr = row0 + srow;
  gr = gr < N_NODES ? gr : N_NODES - 1;   // clamp load; store guarded
  const float*  xrow = &X[(size_t)gr * IN_DIM + sk];
  const ushort* wrow = &WT[(size_t)srow * IN_DIM + sk];

  f32x4 acc[4] = {};

  // prologue: tile-0 loads
  float4 xv0 = *(const float4*)&xrow[0];
  float4 xv1 = *(const float4*)&xrow[4];
  float4 xv2 = *(const float4*)&xrow[8];
  float4 xv3 = *(const float4*)&xrow[12];
  uint4  wv0 = *(const uint4*)&wrow[0];
  uint4  wv1 = *(const uint4*)&wrow[8];

  for (int kt = 0; kt < IN_DIM; kt += 64) {
    ushort xb[16];
    {
      float xv[16] = {xv0.x, xv0.y, xv0.z, xv0.w, xv1.x, xv1.y, xv1.z, xv1.w,
                      xv2.x, xv2.y, xv2.z, xv2.w, xv3.x, xv3.y, xv3.z, xv3.w};
#pragma unroll
      for (int i = 0; i < 16; i++) xb[i] = f2bf(xv[i]);
    }
    *(uint4*)&xs[srow][ch0 * 8] = *(uint4*)&xb[0];
    *(uint4*)&xs[srow][ch1 * 8] = *(uint4*)&xb[8];
    *(uint4*)&ws[srow][ch0 * 8] = wv0;
    *(uint4*)&ws[srow][ch1 * 8] = wv1;
    __syncthreads();

    if (kt + 64 < IN_DIM) {   // prefetch next tile while MFMAs run
      xv0 = *(const float4*)&xrow[kt + 64 + 0];
      xv1 = *(const float4*)&xrow[kt + 64 + 4];
      xv2 = *(const float4*)&xrow[kt + 64 + 8];
      xv3 = *(const float4*)&xrow[kt + 64 + 12];
      wv0 = *(const uint4*)&wrow[kt + 64 + 0];
      wv1 = *(const uint4*)&wrow[kt + 64 + 8];
    }

    const int ar   = wave * 16 + l16;
    const int axor = ar & 7;
#pragma unroll
    for (int ks = 0; ks < 2; ks++) {
      bf16x8 a = *(const bf16x8*)&xs[ar][((ks * 4 + quad) ^ axor) * 8];
#pragma unroll
      for (int ct = 0; ct < 4; ct++) {
        const int br = ct * 16 + l16;
        bf16x8 b = *(const bf16x8*)&ws[br][((ks * 4 + quad) ^ (br & 7)) * 8];
        acc[ct] = __builtin_amdgcn_mfma_f32_16x16x32_bf16(a, b, acc[ct], 0, 0, 0);
      }
    }
    __syncthreads();
  }

  // C/D layout: col = l16, row = quad*4 + reg   [m89-verified]
#pragma unroll
  for (int ct = 0; ct < 4; ct++) {
#pragma unroll
    for (int r = 0; r < 4; r++) {
      int row = row0 + wave * 16 + quad * 4 + r;
      if (row < N_NODES) P[(size_t)row * HID + ct * 16 + l16] = f2bf(acc[ct][r]);
    }
  }
}

// cnt[d] = in-degree; bucket[d*CAP+slot] = src  (built once, reused both layers)
__global__ __launch_bounds__(256) void build_buckets(const int* __restrict__ src,
                                                     const int* __restrict__ dst,
                                                     int* __restrict__ cnt,
                                                     int* __restrict__ bucket) {
  int e = blockIdx.x * 256 + threadIdx.x;
  if (e >= N_EDGES) return;
  int s = src[e];
  int d = dst[e];
  int slot = atomicAdd(&cnt[d], 1);
  if (slot < CAP) bucket[d * CAP + slot] = s;
}

// AGG[n][lane] = bf16( sum over neighbors of fp32(P[src][lane]) ). One wave/node.
__global__ __launch_bounds__(256) void gather_agg(const int* __restrict__ cnt,
                                                  const int* __restrict__ bucket,
                                                  const ushort* __restrict__ P,
                                                  ushort* __restrict__ AGG) {
  int n = blockIdx.x * 4 + (threadIdx.x >> 6);
  n = __builtin_amdgcn_readfirstlane(n);   // wave-uniform -> scalar loads
  int lane = threadIdx.x & 63;
  if (n >= N_NODES) return;
  int c = cnt[n];
  c = c < CAP ? c : CAP;
  const int* b = &bucket[n * CAP];
  float acc = 0.0f;
  int i = 0;
  for (; i + 4 <= c; i += 4) {
    int s0 = b[i + 0], s1 = b[i + 1], s2 = b[i + 2], s3 = b[i + 3];
    float v0 = bf2f(P[(size_t)s0 * HID + lane]);
    float v1 = bf2f(P[(size_t)s1 * HID + lane]);
    float v2 = bf2f(P[(size_t)s2 * HID + lane]);
    float v3 = bf2f(P[(size_t)s3 * HID + lane]);
    acc += (v0 + v1) + (v2 + v3);
  }
  for (; i < c; i++) acc += bf2f(P[(size_t)b[i] * HID + lane]);
  AGG[(size_t)n * HID + lane] = f2bf(acc);
}

// OUT[n,64] = bf16([relu_out]( h @ W + bout )), h = has_bn? relu(BN(A+AGG+bin)) : A
// A/AGG/OUT bf16; GEMM + h in fp32.
__global__ __launch_bounds__(256) void mlp64(
    const ushort* __restrict__ A, const ushort* __restrict__ AGG,
    const float* __restrict__ bin, const float* __restrict__ g,
    const float* __restrict__ be, const float* __restrict__ rm,
    const float* __restrict__ rv, const float* __restrict__ W,
    const float* __restrict__ bout, ushort* __restrict__ OUT,
    int has_bn, int relu_out) {
  __shared__ float hs[64][68];
  __shared__ float ws[64][64];
  __shared__ float sS[64];
  __shared__ float sT[64];
  const int tid  = threadIdx.x;
  const int row0 = blockIdx.x * 64;
  const int tc   = tid & 15;
  const int tr   = tid >> 4;
  const int r0   = tr << 2;
  const int c0   = tc << 2;

  if (tid < 64) {
    if (has_bn) {
      float s = g[tid] * rsqrtf(rv[tid] + BN_EPS);
      sS[tid] = s;
      sT[tid] = (bin[tid] - rm[tid]) * s + be[tid];
    } else {
      sS[tid] = 1.0f;
      sT[tid] = 0.0f;
    }
  }
#pragma unroll
  for (int i = 0; i < 4; i++) {
    int k = tr + 16 * i;
    *(float4*)&ws[k][tc * 4] = *(const float4*)&W[(size_t)k * HID + tc * 4];
  }
  __syncthreads();

  {
    float4 sv = *(const float4*)&sS[tc * 4];
    float4 tv = *(const float4*)&sT[tc * 4];
#pragma unroll
    for (int i = 0; i < 4; i++) {
      int r  = tr + 16 * i;
      int gr = row0 + r;
      gr = gr < N_NODES ? gr : N_NODES - 1;
      ushort4 av = *(const ushort4*)&A[(size_t)gr * HID + tc * 4];
      float4 v = make_float4(bf2f(av.x), bf2f(av.y), bf2f(av.z), bf2f(av.w));
      if (AGG) {
        ushort4 gv = *(const ushort4*)&AGG[(size_t)gr * HID + tc * 4];
        v.x += bf2f(gv.x); v.y += bf2f(gv.y); v.z += bf2f(gv.z); v.w += bf2f(gv.w);
      }
      if (has_bn) {
        v.x = fmaxf(fmaf(v.x, sv.x, tv.x), 0.0f);
        v.y = fmaxf(fmaf(v.y, sv.y, tv.y), 0.0f);
        v.z = fmaxf(fmaf(v.z, sv.z, tv.z), 0.0f);
        v.w = fmaxf(fmaf(v.w, sv.w, tv.w), 0.0f);
      }
      *(float4*)&hs[r][tc * 4] = v;
    }
  }
  __syncthreads();

  float4 acc[4] = {};
#pragma unroll
  for (int k = 0; k < 64; k += 4) {
    float4 a0 = *(const float4*)&hs[r0 + 0][k];
    float4 a1 = *(const float4*)&hs[r0 + 1][k];
    float4 a2 = *(const float4*)&hs[r0 + 2][k];
    float4 a3 = *(const float4*)&hs[r0 + 3][k];
    float4 b0 = *(const float4*)&ws[k + 0][c0];
    float4 b1 = *(const float4*)&ws[k + 1][c0];
    float4 b2 = *(const float4*)&ws[k + 2][c0];
    float4 b3 = *(const float4*)&ws[k + 3][c0];
    fma4(acc[0], a0.x, b0); fma4(acc[0], a0.y, b1); fma4(acc[0], a0.z, b2); fma4(acc[0], a0.w, b3);
    fma4(acc[1], a1.x, b0); fma4(acc[1], a1.y, b1); fma4(acc[1], a1.z, b2); fma4(acc[1], a1.w, b3);
    fma4(acc[2], a2.x, b0); fma4(acc[2], a2.y, b1); fma4(acc[2], a2.z, b2); fma4(acc[2], a2.w, b3);
    fma4(acc[3], a3.x, b0); fma4(acc[3], a3.y, b1); fma4(acc[3], a3.z, b2); fma4(acc[3], a3.w, b3);
  }

  float4 bo = make_float4(0.f, 0.f, 0.f, 0.f);
  if (bout) bo = *(const float4*)&bout[c0];
#pragma unroll
  for (int i = 0; i < 4; i++) {
    int gr = row0 + r0 + i;
    if (gr < N_NODES) {
      float4 v = acc[i];
      v.x += bo.x; v.y += bo.y; v.z += bo.z; v.w += bo.w;
      if (relu_out) {
        v.x = fmaxf(v.x, 0.f); v.y = fmaxf(v.y, 0.f);
        v.z = fmaxf(v.z, 0.f); v.w = fmaxf(v.w, 0.f);
      }
      ushort4 o = make_ushort4(f2bf(v.x), f2bf(v.y), f2bf(v.z), f2bf(v.w));
      *(ushort4*)&OUT[(size_t)gr * HID + c0] = o;
    }
  }
}

__global__ __launch_bounds__(256) void init_out(float* __restrict__ out,
                                                const float* __restrict__ bl) {
  int i = blockIdx.x * 256 + threadIdx.x;
  if (i < N_GRAPHS * 2) out[i] = bl[i & 1];
}

// out[batch[n]] += [x1[n], x2[n]] @ wl   (one wave/node, shuffle reduce, 2 atomics)
__global__ __launch_bounds__(256) void pool(const ushort* __restrict__ x1,
                                            const ushort* __restrict__ x2,
                                            const int* __restrict__ batch,
                                            const float* __restrict__ wl,
                                            float* __restrict__ out) {
  int gt   = blockIdx.x * 256 + threadIdx.x;
  int n    = gt >> 6;
  int lane = threadIdx.x & 63;
  if (n >= N_NODES) return;
  float a = bf2f(x1[(size_t)n * HID + lane]);
  float b = bf2f(x2[(size_t)n * HID + lane]);
  float p0 = a * wl[lane * 2 + 0] + b * wl[(64 + lane) * 2 + 0];
  float p1 = a * wl[lane * 2 + 1] + b * wl[(64 + lane) * 2 + 1];
#pragma unroll
  for (int off = 32; off > 0; off >>= 1) {
    p0 += __shfl_down(p0, off);
    p1 += __shfl_down(p1, off);
  }
  if (lane == 0) {
    int gr = batch[n];
    atomicAdd(&out[gr * 2 + 0], p0);
    atomicAdd(&out[gr * 2 + 1], p1);
  }
}

extern "C" void kernel_launch(void* const* d_in, const int* in_sizes, int n_in,
                              void* d_out, int out_size, void* d_ws, size_t ws_size,
                              hipStream_t stream) {
  const float* x   = (const float*)d_in[0];
  const int*   ei  = (const int*)d_in[1];
  const int*   bat = (const int*)d_in[2];
  const float* w1a = (const float*)d_in[3];
  const float* b1a = (const float*)d_in[4];
  const float* g1  = (const float*)d_in[5];
  const float* be1 = (const float*)d_in[6];
  const float* rm1 = (const float*)d_in[7];
  const float* rv1 = (const float*)d_in[8];
  const float* w1b = (const float*)d_in[9];
  const float* b1b = (const float*)d_in[10];
  const float* w2a = (const float*)d_in[11];
  const float* b2a = (const float*)d_in[12];
  const float* g2  = (const float*)d_in[13];
  const float* be2 = (const float*)d_in[14];
  const float* rm2 = (const float*)d_in[15];
  const float* rv2 = (const float*)d_in[16];
  const float* w2b = (const float*)d_in[17];
  const float* b2b = (const float*)d_in[18];
  const float* wl  = (const float*)d_in[19];
  const float* bl  = (const float*)d_in[20];
  float* out = (float*)d_out;

  const int* src = ei;
  const int* dst = ei + N_EDGES;

  const size_t FB = (size_t)N_NODES * HID;   // feature buffer elems (bf16)
  ushort* P   = (ushort*)d_ws;               // 6.4 MB (p1, then p2)
  ushort* AGG = P + FB;                      // 6.4 MB
  ushort* X1  = AGG + FB;                    // 6.4 MB
  ushort* X2  = X1 + FB;                     // 6.4 MB
  ushort* WT  = X2 + FB;                     // 96 KB bf16 w1a^T
  int* cnt    = (int*)(WT + (size_t)HID * IN_DIM);
  int* bucket = cnt + N_NODES;               // 12.8 MB  (total ~38.7 MB)

  const int GB = (N_NODES + 63) / 64;        // 782
  const int BB = (N_EDGES + 255) / 256;      // 1563
  const int AB = N_NODES / 4;                // 12500 (exact)
  const int PB = N_NODES * 64 / 256;         // 12500 (exact)
  const int CB = (HID * IN_DIM + 255) / 256; // 192

  hipMemsetAsync(cnt, 0, N_NODES * sizeof(int), stream);
  build_buckets<<<BB, 256, 0, stream>>>(src, dst, cnt, bucket);
  convert_w<<<CB, 256, 0, stream>>>(w1a, WT);

  // Layer 1: p1 = x @ w1a (projection BEFORE aggregation), MFMA bf16
  gemm_in_mfma<<<GB, 256, 0, stream>>>(x, WT, P);
  gather_agg<<<AB, 256, 0, stream>>>(cnt, bucket, P, AGG);
  mlp64<<<GB, 256, 0, stream>>>(P, AGG, b1a, g1, be1, rm1, rv1, w1b, b1b,
                                X1, 1, 1);
  // Layer 2: p2 = x1 @ w2a
  mlp64<<<GB, 256, 0, stream>>>(X1, nullptr, nullptr, nullptr, nullptr,
                                nullptr, nullptr, w2a, nullptr, P, 0, 0);
  gather_agg<<<AB, 256, 0, stream>>>(cnt, bucket, P, AGG);
  mlp64<<<GB, 256, 0, stream>>>(P, AGG, b2a, g2, be2, rm2, rv2, w2b, b2b,
                                X2, 1, 1);
  // Pool
  init_out<<<(N_GRAPHS * 2 + 255) / 256, 256, 0, stream>>>(out, bl);
  pool<<<PB, 256, 0, stream>>>(X1, X2, bat, wl, out);
}

// Round 4
// 362.869 us; speedup vs baseline: 3.2392x; 1.4342x over previous
//
#include <hip/hip_runtime.h>

constexpr int N_NODES  = 50000;
constexpr int N_EDGES  = 400000;
constexpr int N_GRAPHS = 512;
constexpr int IN_DIM   = 768;
constexpr int HID      = 64;
constexpr float BN_EPS = 1e-5f;
constexpr int CAP      = 64;   // max in-degree ~27 (Poisson 8); 64 is bulletproof

typedef __attribute__((ext_vector_type(8))) short bf16x8;
typedef __attribute__((ext_vector_type(4))) float f32x4;

__device__ __forceinline__ float bf2f(ushort u) {
  return __uint_as_float((unsigned int)u << 16);
}
__device__ __forceinline__ ushort f2bf(float f) {  // RNE
  unsigned int u = __float_as_uint(f);
  u = (u + 0x7fff + ((u >> 16) & 1)) >> 16;
  return (ushort)u;
}

// One kernel: w1a^T -> WT (bf16), {w1b,w2a,w2b}^T -> WTb[3] (bf16), out = bl bcast
constexpr int W1A_E = HID * IN_DIM;     // 49152
constexpr int WB_E  = HID * HID;        // 4096
__global__ __launch_bounds__(256) void convert_all(
    const float* __restrict__ w1a, const float* __restrict__ w1b,
    const float* __restrict__ w2a, const float* __restrict__ w2b,
    const float* __restrict__ bl,
    ushort* __restrict__ WT, ushort* __restrict__ WT1b,
    ushort* __restrict__ WT2a, ushort* __restrict__ WT2b,
    float* __restrict__ out) {
  int i = blockIdx.x * 256 + threadIdx.x;
  if (i < W1A_E) {
    int c = i / IN_DIM, k = i - c * IN_DIM;
    WT[i] = f2bf(w1a[(size_t)k * HID + c]);
    return;
  }
  int j = i - W1A_E;
  if (j < 3 * WB_E) {
    int w = j / WB_E, r = j - w * WB_E;
    int c = r / HID, k = r - c * HID;
    const float* W = (w == 0) ? w1b : (w == 1) ? w2a : w2b;
    ushort* D = (w == 0) ? WT1b : (w == 1) ? WT2a : WT2b;
    D[r] = f2bf(W[(size_t)k * HID + c]);
    return;
  }
  int o = j - 3 * WB_E;
  if (o < N_GRAPHS * 2) out[o] = bl[o & 1];
}

// P[n,64] = bf16( X[n,768] @ W[768,64] )  via 16x16x32 bf16 MFMA.
__global__ __launch_bounds__(256) void gemm_in_mfma(const float* __restrict__ X,
                                                    const ushort* __restrict__ WT,
                                                    ushort* __restrict__ P) {
  __shared__ ushort xs[64][64];   // [row][k], 16B chunks XOR-swizzled by row&7
  __shared__ ushort ws[64][64];   // [col][k]
  const int tid  = threadIdx.x;
  const int row0 = blockIdx.x * 64;
  const int wave = tid >> 6;
  const int lane = tid & 63;
  const int quad = lane >> 4;
  const int l16  = lane & 15;

  const int srow = tid >> 2;
  const int sk   = (tid & 3) * 16;
  const int ch0  = ((sk >> 3) + 0) ^ (srow & 7);
  const int ch1  = ((sk >> 3) + 1) ^ (srow & 7);

  int gr = row0 + srow;
  gr = gr < N_NODES ? gr : N_NODES - 1;
  const float*  xrow = &X[(size_t)gr * IN_DIM + sk];
  const ushort* wrow = &WT[(size_t)srow * IN_DIM + sk];

  f32x4 acc[4] = {};

  float4 xv0 = *(const float4*)&xrow[0];
  float4 xv1 = *(const float4*)&xrow[4];
  float4 xv2 = *(const float4*)&xrow[8];
  float4 xv3 = *(const float4*)&xrow[12];
  uint4  wv0 = *(const uint4*)&wrow[0];
  uint4  wv1 = *(const uint4*)&wrow[8];

  for (int kt = 0; kt < IN_DIM; kt += 64) {
    ushort xb[16];
    {
      float xv[16] = {xv0.x, xv0.y, xv0.z, xv0.w, xv1.x, xv1.y, xv1.z, xv1.w,
                      xv2.x, xv2.y, xv2.z, xv2.w, xv3.x, xv3.y, xv3.z, xv3.w};
#pragma unroll
      for (int i = 0; i < 16; i++) xb[i] = f2bf(xv[i]);
    }
    *(uint4*)&xs[srow][ch0 * 8] = *(uint4*)&xb[0];
    *(uint4*)&xs[srow][ch1 * 8] = *(uint4*)&xb[8];
    *(uint4*)&ws[srow][ch0 * 8] = wv0;
    *(uint4*)&ws[srow][ch1 * 8] = wv1;
    __syncthreads();

    if (kt + 64 < IN_DIM) {
      xv0 = *(const float4*)&xrow[kt + 64 + 0];
      xv1 = *(const float4*)&xrow[kt + 64 + 4];
      xv2 = *(const float4*)&xrow[kt + 64 + 8];
      xv3 = *(const float4*)&xrow[kt + 64 + 12];
      wv0 = *(const uint4*)&wrow[kt + 64 + 0];
      wv1 = *(const uint4*)&wrow[kt + 64 + 8];
    }

    const int ar   = wave * 16 + l16;
    const int axor = ar & 7;
#pragma unroll
    for (int ks = 0; ks < 2; ks++) {
      bf16x8 a = *(const bf16x8*)&xs[ar][((ks * 4 + quad) ^ axor) * 8];
#pragma unroll
      for (int ct = 0; ct < 4; ct++) {
        const int br = ct * 16 + l16;
        bf16x8 b = *(const bf16x8*)&ws[br][((ks * 4 + quad) ^ (br & 7)) * 8];
        acc[ct] = __builtin_amdgcn_mfma_f32_16x16x32_bf16(a, b, acc[ct], 0, 0, 0);
      }
    }
    __syncthreads();
  }

#pragma unroll
  for (int ct = 0; ct < 4; ct++) {
#pragma unroll
    for (int r = 0; r < 4; r++) {
      int row = row0 + wave * 16 + quad * 4 + r;
      if (row < N_NODES) P[(size_t)row * HID + ct * 16 + l16] = f2bf(acc[ct][r]);
    }
  }
}

__global__ __launch_bounds__(256) void build_buckets(const int* __restrict__ src,
                                                     const int* __restrict__ dst,
                                                     int* __restrict__ cnt,
                                                     int* __restrict__ bucket) {
  int e = blockIdx.x * 256 + threadIdx.x;
  if (e >= N_EDGES) return;
  int s = src[e];
  int d = dst[e];
  int slot = atomicAdd(&cnt[d], 1);
  if (slot < CAP) bucket[d * CAP + slot] = s;
}

// AGG[n][lane] = bf16( sum over neighbors of fp32(P[src][lane]) ). One wave/node.
__global__ __launch_bounds__(256) void gather_agg(const int* __restrict__ cnt,
                                                  const int* __restrict__ bucket,
                                                  const ushort* __restrict__ P,
                                                  ushort* __restrict__ AGG) {
  int n = blockIdx.x * 4 + (threadIdx.x >> 6);
  n = __builtin_amdgcn_readfirstlane(n);
  int lane = threadIdx.x & 63;
  if (n >= N_NODES) return;
  int c = cnt[n];
  c = c < CAP ? c : CAP;
  const int* b = &bucket[n * CAP];
  float acc = 0.0f;
  int i = 0;
  for (; i + 4 <= c; i += 4) {
    int s0 = b[i + 0], s1 = b[i + 1], s2 = b[i + 2], s3 = b[i + 3];
    float v0 = bf2f(P[(size_t)s0 * HID + lane]);
    float v1 = bf2f(P[(size_t)s1 * HID + lane]);
    float v2 = bf2f(P[(size_t)s2 * HID + lane]);
    float v3 = bf2f(P[(size_t)s3 * HID + lane]);
    acc += (v0 + v1) + (v2 + v3);
  }
  for (; i < c; i++) acc += bf2f(P[(size_t)b[i] * HID + lane]);
  AGG[(size_t)n * HID + lane] = f2bf(acc);
}

// OUT[n,64] = bf16([relu]( h @ W + bout )), h = has_bn ? relu(BN(A+AGG+bin)) : A
// MFMA 16x16x32 bf16, 64-row tile, BN/ReLU fused into LDS staging.
__global__ __launch_bounds__(256) void mlp64_mfma(
    const ushort* __restrict__ A, const ushort* __restrict__ AGG,
    const float* __restrict__ bin, const float* __restrict__ g,
    const float* __restrict__ be, const float* __restrict__ rm,
    const float* __restrict__ rv, const ushort* __restrict__ WT,
    const float* __restrict__ bout, ushort* __restrict__ OUT,
    int has_bn, int relu_out) {
  __shared__ ushort xs[64][64];
  __shared__ ushort ws[64][64];
  __shared__ float sS[64], sT[64];
  const int tid  = threadIdx.x;
  const int row0 = blockIdx.x * 64;
  const int srow = tid >> 2;        // 0..63
  const int qc0  = (tid & 3) * 2;   // 16B-chunk pair: {0,1},{2,3},{4,5},{6,7}

  if (tid < 64 && has_bn) {
    float s = g[tid] * rsqrtf(rv[tid] + BN_EPS);
    sS[tid] = s;
    sT[tid] = (bin[tid] - rm[tid]) * s + be[tid];
  }
  // stage W^T (bf16, [col][k])
  {
    uint4 w0 = *(const uint4*)&WT[(size_t)srow * HID + qc0 * 8];
    uint4 w1 = *(const uint4*)&WT[(size_t)srow * HID + qc0 * 8 + 8];
    *(uint4*)&ws[srow][((qc0 + 0) ^ (srow & 7)) * 8] = w0;
    *(uint4*)&ws[srow][((qc0 + 1) ^ (srow & 7)) * 8] = w1;
  }
  __syncthreads();   // sS/sT ready for staging

  // stage h
  {
    int gr = row0 + srow;
    gr = gr < N_NODES ? gr : N_NODES - 1;
    ushort va[16];
    *(uint4*)&va[0] = *(const uint4*)&A[(size_t)gr * HID + qc0 * 8];
    *(uint4*)&va[8] = *(const uint4*)&A[(size_t)gr * HID + qc0 * 8 + 8];
    if (has_bn) {
      ushort vg[16];
      *(uint4*)&vg[0] = *(const uint4*)&AGG[(size_t)gr * HID + qc0 * 8];
      *(uint4*)&vg[8] = *(const uint4*)&AGG[(size_t)gr * HID + qc0 * 8 + 8];
#pragma unroll
      for (int j = 0; j < 16; j++) {
        int col = qc0 * 8 + j;
        float v = bf2f(va[j]) + bf2f(vg[j]);
        v = fmaxf(fmaf(v, sS[col], sT[col]), 0.0f);
        va[j] = f2bf(v);
      }
    }
    *(uint4*)&xs[srow][((qc0 + 0) ^ (srow & 7)) * 8] = *(uint4*)&va[0];
    *(uint4*)&xs[srow][((qc0 + 1) ^ (srow & 7)) * 8] = *(uint4*)&va[8];
  }
  __syncthreads();

  const int wave = tid >> 6, lane = tid & 63, quad = lane >> 4, l16 = lane & 15;
  f32x4 acc[4] = {};
  const int ar   = wave * 16 + l16;
  const int axor = ar & 7;
#pragma unroll
  for (int ks = 0; ks < 2; ks++) {
    bf16x8 a = *(const bf16x8*)&xs[ar][((ks * 4 + quad) ^ axor) * 8];
#pragma unroll
    for (int ct = 0; ct < 4; ct++) {
      const int br = ct * 16 + l16;
      bf16x8 b = *(const bf16x8*)&ws[br][((ks * 4 + quad) ^ (br & 7)) * 8];
      acc[ct] = __builtin_amdgcn_mfma_f32_16x16x32_bf16(a, b, acc[ct], 0, 0, 0);
    }
  }

#pragma unroll
  for (int ct = 0; ct < 4; ct++) {
    const int col = ct * 16 + l16;
    float bo = bout ? bout[col] : 0.0f;
#pragma unroll
    for (int r = 0; r < 4; r++) {
      int row = row0 + wave * 16 + quad * 4 + r;
      if (row < N_NODES) {
        float v = acc[ct][r] + bo;
        if (relu_out) v = fmaxf(v, 0.0f);
        OUT[(size_t)row * HID + col] = f2bf(v);
      }
    }
  }
}

// Segmented pool over sorted batch: per-block LDS accumulate, ~6 global atomics/blk
__global__ __launch_bounds__(256) void pool2(const ushort* __restrict__ x1,
                                             const ushort* __restrict__ x2,
                                             const int* __restrict__ batch,
                                             const float* __restrict__ wl,
                                             float* __restrict__ out) {
  __shared__ float gacc[N_GRAPHS * 2];   // 4 KB
  __shared__ float wl_s[2 * HID * 2];    // 1 KB
  const int tid = threadIdx.x;
#pragma unroll
  for (int i = tid; i < N_GRAPHS * 2; i += 256) gacc[i] = 0.0f;
  wl_s[tid] = wl[tid];                   // exactly 256 floats
  __syncthreads();

  const int wave = tid >> 6, lane = tid & 63;
  const int sub = lane & 3, noff = lane >> 2;
  const int nbase = blockIdx.x * 256 + wave * 64;
#pragma unroll
  for (int it = 0; it < 4; it++) {
    int node = nbase + it * 16 + noff;
    bool ok = node < N_NODES;
    int cn = ok ? node : N_NODES - 1;
    ushort v1[16], v2[16];
    const ushort* r1 = &x1[(size_t)cn * HID + sub * 16];
    const ushort* r2 = &x2[(size_t)cn * HID + sub * 16];
    *(uint4*)&v1[0] = *(const uint4*)&r1[0];
    *(uint4*)&v1[8] = *(const uint4*)&r1[8];
    *(uint4*)&v2[0] = *(const uint4*)&r2[0];
    *(uint4*)&v2[8] = *(const uint4*)&r2[8];
    float p0 = 0.0f, p1 = 0.0f;
#pragma unroll
    for (int j = 0; j < 16; j++) {
      int e = sub * 16 + j;
      float a = bf2f(v1[j]);
      float b = bf2f(v2[j]);
      p0 += a * wl_s[e * 2 + 0] + b * wl_s[(HID + e) * 2 + 0];
      p1 += a * wl_s[e * 2 + 1] + b * wl_s[(HID + e) * 2 + 1];
    }
    p0 += __shfl_xor(p0, 1); p0 += __shfl_xor(p0, 2);
    p1 += __shfl_xor(p1, 1); p1 += __shfl_xor(p1, 2);
    if (sub == 0 && ok) {
      int gr = batch[node];
      atomicAdd(&gacc[gr * 2 + 0], p0);
      atomicAdd(&gacc[gr * 2 + 1], p1);
    }
  }
  __syncthreads();
#pragma unroll
  for (int i = tid; i < N_GRAPHS * 2; i += 256) {
    float v = gacc[i];
    if (v != 0.0f) atomicAdd(&out[i], v);
  }
}

extern "C" void kernel_launch(void* const* d_in, const int* in_sizes, int n_in,
                              void* d_out, int out_size, void* d_ws, size_t ws_size,
                              hipStream_t stream) {
  const float* x   = (const float*)d_in[0];
  const int*   ei  = (const int*)d_in[1];
  const int*   bat = (const int*)d_in[2];
  const float* w1a = (const float*)d_in[3];
  const float* b1a = (const float*)d_in[4];
  const float* g1  = (const float*)d_in[5];
  const float* be1 = (const float*)d_in[6];
  const float* rm1 = (const float*)d_in[7];
  const float* rv1 = (const float*)d_in[8];
  const float* w1b = (const float*)d_in[9];
  const float* b1b = (const float*)d_in[10];
  const float* w2a = (const float*)d_in[11];
  const float* b2a = (const float*)d_in[12];
  const float* g2  = (const float*)d_in[13];
  const float* be2 = (const float*)d_in[14];
  const float* rm2 = (const float*)d_in[15];
  const float* rv2 = (const float*)d_in[16];
  const float* w2b = (const float*)d_in[17];
  const float* b2b = (const float*)d_in[18];
  const float* wl  = (const float*)d_in[19];
  const float* bl  = (const float*)d_in[20];
  float* out = (float*)d_out;

  const int* src = ei;
  const int* dst = ei + N_EDGES;

  const size_t FB = (size_t)N_NODES * HID;
  ushort* P    = (ushort*)d_ws;              // 6.4 MB (p1, then p2)
  ushort* AGG  = P + FB;                     // 6.4 MB
  ushort* X1   = AGG + FB;                   // 6.4 MB
  ushort* X2   = X1 + FB;                    // 6.4 MB
  ushort* WT   = X2 + FB;                    // 96 KB (w1a^T)
  ushort* WT1b = WT + (size_t)W1A_E;         // 8 KB each
  ushort* WT2a = WT1b + WB_E;
  ushort* WT2b = WT2a + WB_E;
  int* cnt     = (int*)(WT2b + WB_E);        // 200 KB
  int* bucket  = cnt + N_NODES;              // 12.8 MB  (total ~38.7 MB)

  const int GB = (N_NODES + 63) / 64;        // 782
  const int BB = (N_EDGES + 255) / 256;      // 1563
  const int AB = N_NODES / 4;                // 12500
  const int PB = (N_NODES + 255) / 256;      // 196
  const int CB = (W1A_E + 3 * WB_E + N_GRAPHS * 2 + 255) / 256;  // 245

  hipMemsetAsync(cnt, 0, N_NODES * sizeof(int), stream);
  build_buckets<<<BB, 256, 0, stream>>>(src, dst, cnt, bucket);
  convert_all<<<CB, 256, 0, stream>>>(w1a, w1b, w2a, w2b, bl,
                                      WT, WT1b, WT2a, WT2b, out);

  // Layer 1: p1 = x @ w1a (projection BEFORE aggregation)
  gemm_in_mfma<<<GB, 256, 0, stream>>>(x, WT, P);
  gather_agg<<<AB, 256, 0, stream>>>(cnt, bucket, P, AGG);
  mlp64_mfma<<<GB, 256, 0, stream>>>(P, AGG, b1a, g1, be1, rm1, rv1, WT1b, b1b,
                                     X1, 1, 1);
  // Layer 2
  mlp64_mfma<<<GB, 256, 0, stream>>>(X1, nullptr, nullptr, nullptr, nullptr,
                                     nullptr, nullptr, WT2a, nullptr, P, 0, 0);
  gather_agg<<<AB, 256, 0, stream>>>(cnt, bucket, P, AGG);
  mlp64_mfma<<<GB, 256, 0, stream>>>(P, AGG, b2a, g2, be2, rm2, rv2, WT2b, b2b,
                                     X2, 1, 1);
  // Pool (segmented; out pre-initialized to bl by convert_all)
  pool2<<<PB, 256, 0, stream>>>(X1, X2, bat, wl, out);
}

// Round 5
// 334.338 us; speedup vs baseline: 3.5156x; 1.0853x over previous
//
#include <hip/hip_runtime.h>

constexpr int N_NODES  = 50000;
constexpr int N_EDGES  = 400000;
constexpr int N_GRAPHS = 512;
constexpr int IN_DIM   = 768;
constexpr int HID      = 64;
constexpr float BN_EPS = 1e-5f;
constexpr int CAP      = 64;   // max in-degree ~27 (Poisson 8); 64 is bulletproof

typedef __attribute__((ext_vector_type(8))) short bf16x8;
typedef __attribute__((ext_vector_type(4))) float f32x4;

__device__ __forceinline__ float bf2f(ushort u) {
  return __uint_as_float((unsigned int)u << 16);
}
__device__ __forceinline__ ushort f2bf(float f) {  // RNE
  unsigned int u = __float_as_uint(f);
  u = (u + 0x7fff + ((u >> 16) & 1)) >> 16;
  return (ushort)u;
}

// w1a^T -> WT, {w1b,w2a,w2b}^T -> WT*b (bf16), out = bl bcast, cnt = 0
constexpr int W1A_E = HID * IN_DIM;     // 49152
constexpr int WB_E  = HID * HID;        // 4096
__global__ __launch_bounds__(256) void convert_all(
    const float* __restrict__ w1a, const float* __restrict__ w1b,
    const float* __restrict__ w2a, const float* __restrict__ w2b,
    const float* __restrict__ bl,
    ushort* __restrict__ WT, ushort* __restrict__ WT1b,
    ushort* __restrict__ WT2a, ushort* __restrict__ WT2b,
    float* __restrict__ out, int* __restrict__ cnt) {
  int i = blockIdx.x * 256 + threadIdx.x;
  if (i < W1A_E) {
    int c = i / IN_DIM, k = i - c * IN_DIM;
    WT[i] = f2bf(w1a[(size_t)k * HID + c]);
    return;
  }
  int j = i - W1A_E;
  if (j < 3 * WB_E) {
    int w = j / WB_E, r = j - w * WB_E;
    int c = r / HID, k = r - c * HID;
    const float* W = (w == 0) ? w1b : (w == 1) ? w2a : w2b;
    ushort* D = (w == 0) ? WT1b : (w == 1) ? WT2a : WT2b;
    D[r] = f2bf(W[(size_t)k * HID + c]);
    return;
  }
  int o = j - 3 * WB_E;
  if (o < N_GRAPHS * 2) { out[o] = bl[o & 1]; return; }
  int z = o - N_GRAPHS * 2;
  if (z < N_NODES) cnt[z] = 0;
}

// P[n,64] = bf16( X[n,768] @ W[768,64] )  via 16x16x32 bf16 MFMA.
__global__ __launch_bounds__(256) void gemm_in_mfma(const float* __restrict__ X,
                                                    const ushort* __restrict__ WT,
                                                    ushort* __restrict__ P) {
  __shared__ ushort xs[64][64];   // [row][k], 16B chunks XOR-swizzled by row&7
  __shared__ ushort ws[64][64];   // [col][k]
  const int tid  = threadIdx.x;
  const int row0 = blockIdx.x * 64;
  const int wave = tid >> 6;
  const int lane = tid & 63;
  const int quad = lane >> 4;
  const int l16  = lane & 15;

  const int srow = tid >> 2;
  const int sk   = (tid & 3) * 16;
  const int ch0  = ((sk >> 3) + 0) ^ (srow & 7);
  const int ch1  = ((sk >> 3) + 1) ^ (srow & 7);

  int gr = row0 + srow;
  gr = gr < N_NODES ? gr : N_NODES - 1;
  const float*  xrow = &X[(size_t)gr * IN_DIM + sk];
  const ushort* wrow = &WT[(size_t)srow * IN_DIM + sk];

  f32x4 acc[4] = {};

  float4 xv0 = *(const float4*)&xrow[0];
  float4 xv1 = *(const float4*)&xrow[4];
  float4 xv2 = *(const float4*)&xrow[8];
  float4 xv3 = *(const float4*)&xrow[12];
  uint4  wv0 = *(const uint4*)&wrow[0];
  uint4  wv1 = *(const uint4*)&wrow[8];

  for (int kt = 0; kt < IN_DIM; kt += 64) {
    ushort xb[16];
    {
      float xv[16] = {xv0.x, xv0.y, xv0.z, xv0.w, xv1.x, xv1.y, xv1.z, xv1.w,
                      xv2.x, xv2.y, xv2.z, xv2.w, xv3.x, xv3.y, xv3.z, xv3.w};
#pragma unroll
      for (int i = 0; i < 16; i++) xb[i] = f2bf(xv[i]);
    }
    *(uint4*)&xs[srow][ch0 * 8] = *(uint4*)&xb[0];
    *(uint4*)&xs[srow][ch1 * 8] = *(uint4*)&xb[8];
    *(uint4*)&ws[srow][ch0 * 8] = wv0;
    *(uint4*)&ws[srow][ch1 * 8] = wv1;
    __syncthreads();

    if (kt + 64 < IN_DIM) {
      xv0 = *(const float4*)&xrow[kt + 64 + 0];
      xv1 = *(const float4*)&xrow[kt + 64 + 4];
      xv2 = *(const float4*)&xrow[kt + 64 + 8];
      xv3 = *(const float4*)&xrow[kt + 64 + 12];
      wv0 = *(const uint4*)&wrow[kt + 64 + 0];
      wv1 = *(const uint4*)&wrow[kt + 64 + 8];
    }

    const int ar   = wave * 16 + l16;
    const int axor = ar & 7;
#pragma unroll
    for (int ks = 0; ks < 2; ks++) {
      bf16x8 a = *(const bf16x8*)&xs[ar][((ks * 4 + quad) ^ axor) * 8];
#pragma unroll
      for (int ct = 0; ct < 4; ct++) {
        const int br = ct * 16 + l16;
        bf16x8 b = *(const bf16x8*)&ws[br][((ks * 4 + quad) ^ (br & 7)) * 8];
        acc[ct] = __builtin_amdgcn_mfma_f32_16x16x32_bf16(a, b, acc[ct], 0, 0, 0);
      }
    }
    __syncthreads();
  }

#pragma unroll
  for (int ct = 0; ct < 4; ct++) {
#pragma unroll
    for (int r = 0; r < 4; r++) {
      int row = row0 + wave * 16 + quad * 4 + r;
      if (row < N_NODES) P[(size_t)row * HID + ct * 16 + l16] = f2bf(acc[ct][r]);
    }
  }
}

__global__ __launch_bounds__(256) void build_buckets(const int* __restrict__ src,
                                                     const int* __restrict__ dst,
                                                     int* __restrict__ cnt,
                                                     int* __restrict__ bucket) {
  int e = blockIdx.x * 256 + threadIdx.x;
  if (e >= N_EDGES) return;
  int s = src[e];
  int d = dst[e];
  int slot = atomicAdd(&cnt[d], 1);
  if (slot < CAP) bucket[d * CAP + slot] = s;
}

// Fused GIN layer: gather(Pin) + BN/ReLU staging + MFMA(WT1)+b1+ReLU -> OUT1.
// CHAIN: additionally OUT2 = OUT1_tile @ WT2^T (raw, no bias) via a 2nd MFMA.
// 64 nodes/block; gather done by 4 threads/node in fp32 during staging.
template <int CHAIN>
__global__ __launch_bounds__(256) void fused_mlp(
    const int* __restrict__ cnt, const int* __restrict__ bucket,
    const ushort* __restrict__ Pin,
    const float* __restrict__ bin, const float* __restrict__ g,
    const float* __restrict__ be, const float* __restrict__ rm,
    const float* __restrict__ rv,
    const ushort* __restrict__ WT1, const float* __restrict__ b1,
    const ushort* __restrict__ WT2,
    ushort* __restrict__ OUT1, ushort* __restrict__ OUT2) {
  __shared__ ushort xs[64][64];   // swizzled A-tile
  __shared__ ushort ws[64][64];   // WT1 [col][k] swizzled
  __shared__ ushort ws2[64][64];  // WT2 (CHAIN only)
  __shared__ float sS[64], sT[64];
  const int tid  = threadIdx.x;
  const int row0 = blockIdx.x * 64;
  const int srow = tid >> 2;        // node-in-tile (staging)
  const int sub  = tid & 3;         // 16-col group
  const int qc0  = sub * 2;         // 16B-chunk pair

  if (tid < 64) {
    float s = g[tid] * rsqrtf(rv[tid] + BN_EPS);
    sS[tid] = s;
    sT[tid] = (bin[tid] - rm[tid]) * s + be[tid];
  }
  {
    uint4 w0 = *(const uint4*)&WT1[(size_t)srow * HID + qc0 * 8];
    uint4 w1 = *(const uint4*)&WT1[(size_t)srow * HID + qc0 * 8 + 8];
    *(uint4*)&ws[srow][((qc0 + 0) ^ (srow & 7)) * 8] = w0;
    *(uint4*)&ws[srow][((qc0 + 1) ^ (srow & 7)) * 8] = w1;
    if (CHAIN) {
      uint4 v0 = *(const uint4*)&WT2[(size_t)srow * HID + qc0 * 8];
      uint4 v1 = *(const uint4*)&WT2[(size_t)srow * HID + qc0 * 8 + 8];
      *(uint4*)&ws2[srow][((qc0 + 0) ^ (srow & 7)) * 8] = v0;
      *(uint4*)&ws2[srow][((qc0 + 1) ^ (srow & 7)) * 8] = v1;
    }
  }
  __syncthreads();   // sS/sT ready

  // ---- gather + BN + ReLU -> stage h into xs ----
  {
    int node = row0 + srow;
    node = node < N_NODES ? node : N_NODES - 1;
    float acc[16];
    {
      ushort b0[16];
      const ushort* base = &Pin[(size_t)node * HID + sub * 16];
      *(uint4*)&b0[0] = *(const uint4*)&base[0];
      *(uint4*)&b0[8] = *(const uint4*)&base[8];
#pragma unroll
      for (int j = 0; j < 16; j++) acc[j] = bf2f(b0[j]);
    }
    int c = cnt[node];
    c = c < CAP ? c : CAP;
    const int* bkt = &bucket[node * CAP];
    int i = 0;
    for (; i + 4 <= c; i += 4) {
      int4 s4 = *(const int4*)&bkt[i];
      ushort r0[16], r1[16], r2[16], r3[16];
      const ushort* p0 = &Pin[(size_t)s4.x * HID + sub * 16];
      const ushort* p1 = &Pin[(size_t)s4.y * HID + sub * 16];
      const ushort* p2 = &Pin[(size_t)s4.z * HID + sub * 16];
      const ushort* p3 = &Pin[(size_t)s4.w * HID + sub * 16];
      *(uint4*)&r0[0] = *(const uint4*)&p0[0]; *(uint4*)&r0[8] = *(const uint4*)&p0[8];
      *(uint4*)&r1[0] = *(const uint4*)&p1[0]; *(uint4*)&r1[8] = *(const uint4*)&p1[8];
      *(uint4*)&r2[0] = *(const uint4*)&p2[0]; *(uint4*)&r2[8] = *(const uint4*)&p2[8];
      *(uint4*)&r3[0] = *(const uint4*)&p3[0]; *(uint4*)&r3[8] = *(const uint4*)&p3[8];
#pragma unroll
      for (int j = 0; j < 16; j++)
        acc[j] += (bf2f(r0[j]) + bf2f(r1[j])) + (bf2f(r2[j]) + bf2f(r3[j]));
    }
    for (; i < c; i++) {
      const ushort* p0 = &Pin[(size_t)bkt[i] * HID + sub * 16];
      ushort r0[16];
      *(uint4*)&r0[0] = *(const uint4*)&p0[0]; *(uint4*)&r0[8] = *(const uint4*)&p0[8];
#pragma unroll
      for (int j = 0; j < 16; j++) acc[j] += bf2f(r0[j]);
    }
    // BN + ReLU (agg kept in fp32 end-to-end)
    ushort hb[16];
#pragma unroll
    for (int j = 0; j < 16; j++) {
      int col = sub * 16 + j;
      float v = fmaxf(fmaf(acc[j], sS[col], sT[col]), 0.0f);
      hb[j] = f2bf(v);
    }
    *(uint4*)&xs[srow][((qc0 + 0) ^ (srow & 7)) * 8] = *(uint4*)&hb[0];
    *(uint4*)&xs[srow][((qc0 + 1) ^ (srow & 7)) * 8] = *(uint4*)&hb[8];
  }
  __syncthreads();

  const int wave = tid >> 6, lane = tid & 63, quad = lane >> 4, l16 = lane & 15;
  const int ar = wave * 16 + l16, axor = ar & 7;

  // ---- GEMM 1: h @ W1 ----
  f32x4 acc1[4] = {};
#pragma unroll
  for (int ks = 0; ks < 2; ks++) {
    bf16x8 a = *(const bf16x8*)&xs[ar][((ks * 4 + quad) ^ axor) * 8];
#pragma unroll
    for (int ct = 0; ct < 4; ct++) {
      const int br = ct * 16 + l16;
      bf16x8 b = *(const bf16x8*)&ws[br][((ks * 4 + quad) ^ (br & 7)) * 8];
      acc1[ct] = __builtin_amdgcn_mfma_f32_16x16x32_bf16(a, b, acc1[ct], 0, 0, 0);
    }
  }

  if (CHAIN) __syncthreads();   // all xs reads done before overwrite

  // epilogue 1: +bias, ReLU, store OUT1; CHAIN: also restage into xs
  ushort hv[4][4];
#pragma unroll
  for (int ct = 0; ct < 4; ct++) {
    const int col = ct * 16 + l16;
    const float bo = b1[col];
#pragma unroll
    for (int r = 0; r < 4; r++) {
      int lrow = wave * 16 + quad * 4 + r;
      int grow = row0 + lrow;
      float v = fmaxf(acc1[ct][r] + bo, 0.0f);
      ushort h = f2bf(v);
      hv[ct][r] = h;
      if (grow < N_NODES) OUT1[(size_t)grow * HID + col] = h;
    }
  }

  if (CHAIN) {
#pragma unroll
    for (int ct = 0; ct < 4; ct++) {
      const int col = ct * 16 + l16;
#pragma unroll
      for (int r = 0; r < 4; r++) {
        int lrow = wave * 16 + quad * 4 + r;
        xs[lrow][(((col >> 3) ^ (lrow & 7)) * 8) + (col & 7)] = hv[ct][r];
      }
    }
    __syncthreads();

    // ---- GEMM 2: X1 @ W2 (raw pre-aggregation projection) ----
    f32x4 acc2[4] = {};
#pragma unroll
    for (int ks = 0; ks < 2; ks++) {
      bf16x8 a = *(const bf16x8*)&xs[ar][((ks * 4 + quad) ^ axor) * 8];
#pragma unroll
      for (int ct = 0; ct < 4; ct++) {
        const int br = ct * 16 + l16;
        bf16x8 b = *(const bf16x8*)&ws2[br][((ks * 4 + quad) ^ (br & 7)) * 8];
        acc2[ct] = __builtin_amdgcn_mfma_f32_16x16x32_bf16(a, b, acc2[ct], 0, 0, 0);
      }
    }
#pragma unroll
    for (int ct = 0; ct < 4; ct++) {
      const int col = ct * 16 + l16;
#pragma unroll
      for (int r = 0; r < 4; r++) {
        int grow = row0 + wave * 16 + quad * 4 + r;
        if (grow < N_NODES) OUT2[(size_t)grow * HID + col] = f2bf(acc2[ct][r]);
      }
    }
  }
}

// Segmented pool over sorted batch: per-block LDS accumulate, few global atomics
__global__ __launch_bounds__(256) void pool2(const ushort* __restrict__ x1,
                                             const ushort* __restrict__ x2,
                                             const int* __restrict__ batch,
                                             const float* __restrict__ wl,
                                             float* __restrict__ out) {
  __shared__ float gacc[N_GRAPHS * 2];   // 4 KB
  __shared__ float wl_s[2 * HID * 2];    // 1 KB
  const int tid = threadIdx.x;
#pragma unroll
  for (int i = tid; i < N_GRAPHS * 2; i += 256) gacc[i] = 0.0f;
  wl_s[tid] = wl[tid];                   // exactly 256 floats
  __syncthreads();

  const int wave = tid >> 6, lane = tid & 63;
  const int sub = lane & 3, noff = lane >> 2;
  const int nbase = blockIdx.x * 256 + wave * 64;
#pragma unroll
  for (int it = 0; it < 4; it++) {
    int node = nbase + it * 16 + noff;
    bool ok = node < N_NODES;
    int cn = ok ? node : N_NODES - 1;
    ushort v1[16], v2[16];
    const ushort* r1 = &x1[(size_t)cn * HID + sub * 16];
    const ushort* r2 = &x2[(size_t)cn * HID + sub * 16];
    *(uint4*)&v1[0] = *(const uint4*)&r1[0];
    *(uint4*)&v1[8] = *(const uint4*)&r1[8];
    *(uint4*)&v2[0] = *(const uint4*)&r2[0];
    *(uint4*)&v2[8] = *(const uint4*)&r2[8];
    float p0 = 0.0f, p1 = 0.0f;
#pragma unroll
    for (int j = 0; j < 16; j++) {
      int e = sub * 16 + j;
      float a = bf2f(v1[j]);
      float b = bf2f(v2[j]);
      p0 += a * wl_s[e * 2 + 0] + b * wl_s[(HID + e) * 2 + 0];
      p1 += a * wl_s[e * 2 + 1] + b * wl_s[(HID + e) * 2 + 1];
    }
    p0 += __shfl_xor(p0, 1); p0 += __shfl_xor(p0, 2);
    p1 += __shfl_xor(p1, 1); p1 += __shfl_xor(p1, 2);
    if (sub == 0 && ok) {
      int gr = batch[node];
      atomicAdd(&gacc[gr * 2 + 0], p0);
      atomicAdd(&gacc[gr * 2 + 1], p1);
    }
  }
  __syncthreads();
#pragma unroll
  for (int i = tid; i < N_GRAPHS * 2; i += 256) {
    float v = gacc[i];
    if (v != 0.0f) atomicAdd(&out[i], v);
  }
}

extern "C" void kernel_launch(void* const* d_in, const int* in_sizes, int n_in,
                              void* d_out, int out_size, void* d_ws, size_t ws_size,
                              hipStream_t stream) {
  const float* x   = (const float*)d_in[0];
  const int*   ei  = (const int*)d_in[1];
  const int*   bat = (const int*)d_in[2];
  const float* w1a = (const float*)d_in[3];
  const float* b1a = (const float*)d_in[4];
  const float* g1  = (const float*)d_in[5];
  const float* be1 = (const float*)d_in[6];
  const float* rm1 = (const float*)d_in[7];
  const float* rv1 = (const float*)d_in[8];
  const float* w1b = (const float*)d_in[9];
  const float* b1b = (const float*)d_in[10];
  const float* w2a = (const float*)d_in[11];
  const float* b2a = (const float*)d_in[12];
  const float* g2  = (const float*)d_in[13];
  const float* be2 = (const float*)d_in[14];
  const float* rm2 = (const float*)d_in[15];
  const float* rv2 = (const float*)d_in[16];
  const float* w2b = (const float*)d_in[17];
  const float* b2b = (const float*)d_in[18];
  const float* wl  = (const float*)d_in[19];
  const float* bl  = (const float*)d_in[20];
  float* out = (float*)d_out;

  const int* src = ei;
  const int* dst = ei + N_EDGES;

  const size_t FB = (size_t)N_NODES * HID;
  ushort* P1   = (ushort*)d_ws;              // 6.4 MB
  ushort* P2   = P1 + FB;                    // 6.4 MB
  ushort* X1   = P2 + FB;                    // 6.4 MB
  ushort* X2   = X1 + FB;                    // 6.4 MB
  ushort* WT   = X2 + FB;                    // 96 KB (w1a^T)
  ushort* WT1b = WT + (size_t)W1A_E;         // 8 KB each
  ushort* WT2a = WT1b + WB_E;
  ushort* WT2b = WT2a + WB_E;
  int* cnt     = (int*)(WT2b + WB_E);        // 200 KB
  int* bucket  = cnt + N_NODES;              // 12.8 MB  (total ~39 MB)

  const int GB = (N_NODES + 63) / 64;        // 782
  const int BB = (N_EDGES + 255) / 256;      // 1563
  const int PB = (N_NODES + 255) / 256;      // 196
  const int CB = (W1A_E + 3 * WB_E + N_GRAPHS * 2 + N_NODES + 255) / 256;

  // weights->bf16^T, out=bl, cnt=0 (one kernel), then bucket build
  convert_all<<<CB, 256, 0, stream>>>(w1a, w1b, w2a, w2b, bl,
                                      WT, WT1b, WT2a, WT2b, out, cnt);
  build_buckets<<<BB, 256, 0, stream>>>(src, dst, cnt, bucket);

  // P1 = x @ w1a  (projection BEFORE aggregation — linearity)
  gemm_in_mfma<<<GB, 256, 0, stream>>>(x, WT, P1);
  // Layer 1 fused: gather(P1)+BN+ReLU, @w1b+b1b+ReLU -> X1; chain: P2 = X1@w2a
  fused_mlp<1><<<GB, 256, 0, stream>>>(cnt, bucket, P1, b1a, g1, be1, rm1, rv1,
                                       WT1b, b1b, WT2a, X1, P2);
  // Layer 2 fused: gather(P2)+BN+ReLU, @w2b+b2b+ReLU -> X2
  fused_mlp<0><<<GB, 256, 0, stream>>>(cnt, bucket, P2, b2a, g2, be2, rm2, rv2,
                                       WT2b, b2b, nullptr, X2, nullptr);
  // Pool (out pre-initialized to bl by convert_all)
  pool2<<<PB, 256, 0, stream>>>(X1, X2, bat, wl, out);
}

// Round 7
// 328.224 us; speedup vs baseline: 3.5811x; 1.0186x over previous
//
#include <hip/hip_runtime.h>

constexpr int N_NODES  = 50000;
constexpr int N_EDGES  = 400000;
constexpr int N_GRAPHS = 512;
constexpr int IN_DIM   = 768;
constexpr int HID      = 64;
constexpr float BN_EPS = 1e-5f;
constexpr int CAP      = 64;   // max in-degree ~27 (Poisson 8); 64 is bulletproof

typedef __attribute__((ext_vector_type(8))) short bf16x8;
typedef __attribute__((ext_vector_type(4))) float f32x4;

__device__ __forceinline__ float bf2f(ushort u) {
  return __uint_as_float((unsigned int)u << 16);
}
__device__ __forceinline__ ushort f2bf(float f) {  // RNE
  unsigned int u = __float_as_uint(f);
  u = (u + 0x7fff + ((u >> 16) & 1)) >> 16;
  return (ushort)u;
}

// w1a^T -> WT, {w1b,w2a,w2b}^T -> WT*b (bf16), out = bl bcast, cnt = 0
constexpr int W1A_E = HID * IN_DIM;     // 49152
constexpr int WB_E  = HID * HID;        // 4096
__global__ __launch_bounds__(256) void convert_all(
    const float* __restrict__ w1a, const float* __restrict__ w1b,
    const float* __restrict__ w2a, const float* __restrict__ w2b,
    const float* __restrict__ bl,
    ushort* __restrict__ WT, ushort* __restrict__ WT1b,
    ushort* __restrict__ WT2a, ushort* __restrict__ WT2b,
    float* __restrict__ out, int* __restrict__ cnt) {
  int i = blockIdx.x * 256 + threadIdx.x;
  if (i < W1A_E) {
    int c = i / IN_DIM, k = i - c * IN_DIM;
    WT[i] = f2bf(w1a[(size_t)k * HID + c]);
    return;
  }
  int j = i - W1A_E;
  if (j < 3 * WB_E) {
    int w = j / WB_E, r = j - w * WB_E;
    int c = r / HID, k = r - c * HID;
    const float* W = (w == 0) ? w1b : (w == 1) ? w2a : w2b;
    ushort* D = (w == 0) ? WT1b : (w == 1) ? WT2a : WT2b;
    D[r] = f2bf(W[(size_t)k * HID + c]);
    return;
  }
  int o = j - 3 * WB_E;
  if (o < N_GRAPHS * 2) { out[o] = bl[o & 1]; return; }
  int z = o - N_GRAPHS * 2;
  if (z < N_NODES) cnt[z] = 0;
}

// P[n,64] = bf16( X[n,768] @ W[768,64] ), 128-row tiles, 16x16x32 bf16 MFMA.
__global__ __launch_bounds__(256) void gemm_in_mfma(const float* __restrict__ X,
                                                    const ushort* __restrict__ WT,
                                                    ushort* __restrict__ P) {
  __shared__ ushort xs[128][64];   // [row][k], 16B chunks XOR-swizzled by row&7
  __shared__ ushort ws[64][64];    // [col][k]
  const int tid  = threadIdx.x;
  const int row0 = blockIdx.x * 128;
  const int wave = tid >> 6, lane = tid & 63, quad = lane >> 4, l16 = lane & 15;

  // X staging: 2 threads/row, 32 k-cols each
  const int srow = tid >> 1;
  const int sk   = (tid & 1) * 32;
  int gr = row0 + srow;
  gr = gr < N_NODES ? gr : N_NODES - 1;
  const float* xrow = &X[(size_t)gr * IN_DIM + sk];
  // WT staging: 4 threads/col, TWO 16B chunks each (8 chunks per 64-elem row)
  const int wrow = tid >> 2;
  const int wc0  = (tid & 3) * 2;          // chunk pair {0,1},{2,3},{4,5},{6,7}
  const ushort* wrp = &WT[(size_t)wrow * IN_DIM + wc0 * 8];

  f32x4 acc[2][4] = {};

  float4 xv[8];
#pragma unroll
  for (int i = 0; i < 8; i++) xv[i] = *(const float4*)&xrow[i * 4];
  uint4 wv0 = *(const uint4*)&wrp[0];
  uint4 wv1 = *(const uint4*)&wrp[8];

  for (int kt = 0; kt < IN_DIM; kt += 64) {
    ushort xb[32];
#pragma unroll
    for (int i = 0; i < 8; i++) {
      xb[i * 4 + 0] = f2bf(xv[i].x);
      xb[i * 4 + 1] = f2bf(xv[i].y);
      xb[i * 4 + 2] = f2bf(xv[i].z);
      xb[i * 4 + 3] = f2bf(xv[i].w);
    }
#pragma unroll
    for (int j = 0; j < 4; j++)
      *(uint4*)&xs[srow][(((sk >> 3) + j) ^ (srow & 7)) * 8] = *(uint4*)&xb[j * 8];
    *(uint4*)&ws[wrow][((wc0 + 0) ^ (wrow & 7)) * 8] = wv0;
    *(uint4*)&ws[wrow][((wc0 + 1) ^ (wrow & 7)) * 8] = wv1;
    __syncthreads();

    if (kt + 64 < IN_DIM) {
#pragma unroll
      for (int i = 0; i < 8; i++) xv[i] = *(const float4*)&xrow[kt + 64 + i * 4];
      wv0 = *(const uint4*)&wrp[kt + 64];
      wv1 = *(const uint4*)&wrp[kt + 64 + 8];
    }

    const int ar0 = wave * 32 + l16;
    const int ar1 = ar0 + 16;
#pragma unroll
    for (int ks = 0; ks < 2; ks++) {
      bf16x8 a0 = *(const bf16x8*)&xs[ar0][((ks * 4 + quad) ^ (ar0 & 7)) * 8];
      bf16x8 a1 = *(const bf16x8*)&xs[ar1][((ks * 4 + quad) ^ (ar1 & 7)) * 8];
#pragma unroll
      for (int ct = 0; ct < 4; ct++) {
        const int br = ct * 16 + l16;
        bf16x8 b = *(const bf16x8*)&ws[br][((ks * 4 + quad) ^ (br & 7)) * 8];
        acc[0][ct] = __builtin_amdgcn_mfma_f32_16x16x32_bf16(a0, b, acc[0][ct], 0, 0, 0);
        acc[1][ct] = __builtin_amdgcn_mfma_f32_16x16x32_bf16(a1, b, acc[1][ct], 0, 0, 0);
      }
    }
    __syncthreads();
  }

#pragma unroll
  for (int g2 = 0; g2 < 2; g2++)
#pragma unroll
    for (int ct = 0; ct < 4; ct++)
#pragma unroll
      for (int r = 0; r < 4; r++) {
        int row = row0 + wave * 32 + g2 * 16 + quad * 4 + r;
        if (row < N_NODES)
          P[(size_t)row * HID + ct * 16 + l16] = f2bf(acc[g2][ct][r]);
      }
}

__global__ __launch_bounds__(256) void build_buckets(const int* __restrict__ src,
                                                     const int* __restrict__ dst,
                                                     int* __restrict__ cnt,
                                                     int* __restrict__ bucket) {
  int e = blockIdx.x * 256 + threadIdx.x;
  if (e >= N_EDGES) return;
  int s = src[e];
  int d = dst[e];
  int slot = atomicAdd(&cnt[d], 1);
  if (slot < CAP) bucket[d * CAP + slot] = s;
}

// Fused GIN layer: gather(Pin)+BN/ReLU staging + MFMA(WT1)+b1+ReLU = xL (regs),
// pool partial: out[batch[n]] += xL[n] . wlh  (LDS gacc -> few global atomics).
// CHAIN: additionally OUT2 = xL_tile @ WT2 (raw) via a 2nd MFMA.
template <int CHAIN>
__global__ __launch_bounds__(256) void fused_mlp(
    const int* __restrict__ cnt, const int* __restrict__ bucket,
    const ushort* __restrict__ Pin,
    const float* __restrict__ bin, const float* __restrict__ g,
    const float* __restrict__ be, const float* __restrict__ rm,
    const float* __restrict__ rv,
    const ushort* __restrict__ WT1, const float* __restrict__ b1,
    const ushort* __restrict__ WT2, ushort* __restrict__ OUT2,
    const int* __restrict__ batch, const float* __restrict__ wlh,
    float* __restrict__ out) {
  __shared__ ushort xs[64][64];             // swizzled A-tile
  __shared__ ushort ws[64][64];             // WT1 [col][k] swizzled
  __shared__ ushort ws2[CHAIN ? 64 : 1][64];// WT2 (CHAIN only)
  __shared__ float sS[64], sT[64];
  __shared__ float gacc[N_GRAPHS * 2];      // 4 KB per-block graph accumulators
  __shared__ float wl_s[2 * HID];           // this layer's half of wl: [64][2]
  const int tid  = threadIdx.x;
  const int row0 = blockIdx.x * 64;
  const int srow = tid >> 2;        // node-in-tile (staging)
  const int sub  = tid & 3;         // 16-col group
  const int qc0  = sub * 2;         // 16B-chunk pair

#pragma unroll
  for (int i = tid; i < N_GRAPHS * 2; i += 256) gacc[i] = 0.0f;
  if (tid < 2 * HID) wl_s[tid] = wlh[tid];
  if (tid < 64) {
    float s = g[tid] * rsqrtf(rv[tid] + BN_EPS);
    sS[tid] = s;
    sT[tid] = (bin[tid] - rm[tid]) * s + be[tid];
  }
  {
    uint4 w0 = *(const uint4*)&WT1[(size_t)srow * HID + qc0 * 8];
    uint4 w1 = *(const uint4*)&WT1[(size_t)srow * HID + qc0 * 8 + 8];
    *(uint4*)&ws[srow][((qc0 + 0) ^ (srow & 7)) * 8] = w0;
    *(uint4*)&ws[srow][((qc0 + 1) ^ (srow & 7)) * 8] = w1;
    if (CHAIN) {
      uint4 v0 = *(const uint4*)&WT2[(size_t)srow * HID + qc0 * 8];
      uint4 v1 = *(const uint4*)&WT2[(size_t)srow * HID + qc0 * 8 + 8];
      *(uint4*)&ws2[srow][((qc0 + 0) ^ (srow & 7)) * 8] = v0;
      *(uint4*)&ws2[srow][((qc0 + 1) ^ (srow & 7)) * 8] = v1;
    }
  }
  __syncthreads();   // sS/sT/gacc/wl_s ready

  // ---- gather + BN + ReLU -> stage h into xs (4 threads/node, fp32 agg) ----
  {
    int node = row0 + srow;
    node = node < N_NODES ? node : N_NODES - 1;
    float acc[16];
    {
      ushort b0[16];
      const ushort* base = &Pin[(size_t)node * HID + sub * 16];
      *(uint4*)&b0[0] = *(const uint4*)&base[0];
      *(uint4*)&b0[8] = *(const uint4*)&base[8];
#pragma unroll
      for (int j = 0; j < 16; j++) acc[j] = bf2f(b0[j]);
    }
    int c = cnt[node];
    c = c < CAP ? c : CAP;
    const int* bkt = &bucket[node * CAP];
    int i = 0;
    for (; i + 4 <= c; i += 4) {
      int4 s4 = *(const int4*)&bkt[i];
      ushort r0[16], r1[16], r2[16], r3[16];
      const ushort* p0 = &Pin[(size_t)s4.x * HID + sub * 16];
      const ushort* p1 = &Pin[(size_t)s4.y * HID + sub * 16];
      const ushort* p2 = &Pin[(size_t)s4.z * HID + sub * 16];
      const ushort* p3 = &Pin[(size_t)s4.w * HID + sub * 16];
      *(uint4*)&r0[0] = *(const uint4*)&p0[0]; *(uint4*)&r0[8] = *(const uint4*)&p0[8];
      *(uint4*)&r1[0] = *(const uint4*)&p1[0]; *(uint4*)&r1[8] = *(const uint4*)&p1[8];
      *(uint4*)&r2[0] = *(const uint4*)&p2[0]; *(uint4*)&r2[8] = *(const uint4*)&p2[8];
      *(uint4*)&r3[0] = *(const uint4*)&p3[0]; *(uint4*)&r3[8] = *(const uint4*)&p3[8];
#pragma unroll
      for (int j = 0; j < 16; j++)
        acc[j] += (bf2f(r0[j]) + bf2f(r1[j])) + (bf2f(r2[j]) + bf2f(r3[j]));
    }
    for (; i < c; i++) {
      const ushort* p0 = &Pin[(size_t)bkt[i] * HID + sub * 16];
      ushort r0[16];
      *(uint4*)&r0[0] = *(const uint4*)&p0[0]; *(uint4*)&r0[8] = *(const uint4*)&p0[8];
#pragma unroll
      for (int j = 0; j < 16; j++) acc[j] += bf2f(r0[j]);
    }
    ushort hb[16];
#pragma unroll
    for (int j = 0; j < 16; j++) {
      int col = sub * 16 + j;
      float v = fmaxf(fmaf(acc[j], sS[col], sT[col]), 0.0f);
      hb[j] = f2bf(v);
    }
    *(uint4*)&xs[srow][((qc0 + 0) ^ (srow & 7)) * 8] = *(uint4*)&hb[0];
    *(uint4*)&xs[srow][((qc0 + 1) ^ (srow & 7)) * 8] = *(uint4*)&hb[8];
  }
  __syncthreads();

  const int wave = tid >> 6, lane = tid & 63, quad = lane >> 4, l16 = lane & 15;
  const int ar = wave * 16 + l16, axor = ar & 7;

  // ---- GEMM 1: h @ W1 ----
  f32x4 acc1[4] = {};
#pragma unroll
  for (int ks = 0; ks < 2; ks++) {
    bf16x8 a = *(const bf16x8*)&xs[ar][((ks * 4 + quad) ^ axor) * 8];
#pragma unroll
    for (int ct = 0; ct < 4; ct++) {
      const int br = ct * 16 + l16;
      bf16x8 b = *(const bf16x8*)&ws[br][((ks * 4 + quad) ^ (br & 7)) * 8];
      acc1[ct] = __builtin_amdgcn_mfma_f32_16x16x32_bf16(a, b, acc1[ct], 0, 0, 0);
    }
  }

  if (CHAIN) __syncthreads();   // all xs reads done before restage overwrite

  // epilogue: xL = relu(acc1 + b1) in fp32 regs (C layout: col=ct*16+l16, row=quad*4+r)
  float v[4][4];
#pragma unroll
  for (int ct = 0; ct < 4; ct++) {
    const float bo = b1[ct * 16 + l16];
#pragma unroll
    for (int r = 0; r < 4; r++) v[ct][r] = fmaxf(acc1[ct][r] + bo, 0.0f);
  }

  // ---- fused pool partial: p[r] = xL[row] . wlh ----
  {
    float p0[4] = {}, p1[4] = {};
#pragma unroll
    for (int ct = 0; ct < 4; ct++) {
      const int col = ct * 16 + l16;
      const float w0 = wl_s[col * 2 + 0], w1 = wl_s[col * 2 + 1];
#pragma unroll
      for (int r = 0; r < 4; r++) {
        p0[r] = fmaf(v[ct][r], w0, p0[r]);
        p1[r] = fmaf(v[ct][r], w1, p1[r]);
      }
    }
#pragma unroll
    for (int m = 1; m < 16; m <<= 1) {
#pragma unroll
      for (int r = 0; r < 4; r++) {
        p0[r] += __shfl_xor(p0[r], m);
        p1[r] += __shfl_xor(p1[r], m);
      }
    }
    if (l16 == 0) {
#pragma unroll
      for (int r = 0; r < 4; r++) {
        int node = row0 + wave * 16 + quad * 4 + r;
        if (node < N_NODES) {
          int gi = batch[node];
          atomicAdd(&gacc[gi * 2 + 0], p0[r]);
          atomicAdd(&gacc[gi * 2 + 1], p1[r]);
        }
      }
    }
  }

  if (CHAIN) {
    // restage bf16(xL) into xs, then GEMM 2: xL @ W2 -> OUT2 (raw projection)
#pragma unroll
    for (int ct = 0; ct < 4; ct++) {
      const int col = ct * 16 + l16;
#pragma unroll
      for (int r = 0; r < 4; r++) {
        int lrow = wave * 16 + quad * 4 + r;
        xs[lrow][(((col >> 3) ^ (lrow & 7)) * 8) + (col & 7)] = f2bf(v[ct][r]);
      }
    }
    __syncthreads();

    f32x4 acc2[4] = {};
#pragma unroll
    for (int ks = 0; ks < 2; ks++) {
      bf16x8 a = *(const bf16x8*)&xs[ar][((ks * 4 + quad) ^ axor) * 8];
#pragma unroll
      for (int ct = 0; ct < 4; ct++) {
        const int br = ct * 16 + l16;
        bf16x8 b = *(const bf16x8*)&ws2[br][((ks * 4 + quad) ^ (br & 7)) * 8];
        acc2[ct] = __builtin_amdgcn_mfma_f32_16x16x32_bf16(a, b, acc2[ct], 0, 0, 0);
      }
    }
#pragma unroll
    for (int ct = 0; ct < 4; ct++) {
      const int col = ct * 16 + l16;
#pragma unroll
      for (int r = 0; r < 4; r++) {
        int grow = row0 + wave * 16 + quad * 4 + r;
        if (grow < N_NODES) OUT2[(size_t)grow * HID + col] = f2bf(acc2[ct][r]);
      }
    }
  }

  // ---- flush per-block graph partials (few nonzero: batch is sorted) ----
  __syncthreads();
#pragma unroll
  for (int i = tid; i < N_GRAPHS * 2; i += 256) {
    float vv = gacc[i];
    if (vv != 0.0f) atomicAdd(&out[i], vv);
  }
}

extern "C" void kernel_launch(void* const* d_in, const int* in_sizes, int n_in,
                              void* d_out, int out_size, void* d_ws, size_t ws_size,
                              hipStream_t stream) {
  const float* x   = (const float*)d_in[0];
  const int*   ei  = (const int*)d_in[1];
  const int*   bat = (const int*)d_in[2];
  const float* w1a = (const float*)d_in[3];
  const float* b1a = (const float*)d_in[4];
  const float* g1  = (const float*)d_in[5];
  const float* be1 = (const float*)d_in[6];
  const float* rm1 = (const float*)d_in[7];
  const float* rv1 = (const float*)d_in[8];
  const float* w1b = (const float*)d_in[9];
  const float* b1b = (const float*)d_in[10];
  const float* w2a = (const float*)d_in[11];
  const float* b2a = (const float*)d_in[12];
  const float* g2  = (const float*)d_in[13];
  const float* be2 = (const float*)d_in[14];
  const float* rm2 = (const float*)d_in[15];
  const float* rv2 = (const float*)d_in[16];
  const float* w2b = (const float*)d_in[17];
  const float* b2b = (const float*)d_in[18];
  const float* wl  = (const float*)d_in[19];
  const float* bl  = (const float*)d_in[20];
  float* out = (float*)d_out;

  const int* src = ei;
  const int* dst = ei + N_EDGES;

  const size_t FB = (size_t)N_NODES * HID;
  ushort* P1   = (ushort*)d_ws;              // 6.4 MB
  ushort* P2   = P1 + FB;                    // 6.4 MB
  ushort* WT   = P2 + FB;                    // 96 KB (w1a^T)
  ushort* WT1b = WT + (size_t)W1A_E;         // 8 KB each
  ushort* WT2a = WT1b + WB_E;
  ushort* WT2b = WT2a + WB_E;
  int* cnt     = (int*)(WT2b + WB_E);        // 200 KB
  int* bucket  = cnt + N_NODES;              // 12.8 MB  (total ~26 MB)

  const int GB1 = (N_NODES + 127) / 128;     // 391 (gemm_in, 128-row tiles)
  const int GBF = (N_NODES + 63) / 64;       // 782 (fused layers)
  const int BB  = (N_EDGES + 255) / 256;     // 1563
  const int CB  = (W1A_E + 3 * WB_E + N_GRAPHS * 2 + N_NODES + 255) / 256;

  // weights->bf16^T, out=bl, cnt=0, then bucket build
  convert_all<<<CB, 256, 0, stream>>>(w1a, w1b, w2a, w2b, bl,
                                      WT, WT1b, WT2a, WT2b, out, cnt);
  build_buckets<<<BB, 256, 0, stream>>>(src, dst, cnt, bucket);

  // P1 = x @ w1a  (projection BEFORE aggregation — linearity)
  gemm_in_mfma<<<GB1, 256, 0, stream>>>(x, WT, P1);
  // Layer 1: gather(P1)+BN+ReLU, @w1b+b1b+ReLU = x1 (regs); pool x1.wl[0:64];
  //          chain P2 = x1 @ w2a
  fused_mlp<1><<<GBF, 256, 0, stream>>>(cnt, bucket, P1, b1a, g1, be1, rm1, rv1,
                                        WT1b, b1b, WT2a, P2, bat, wl, out);
  // Layer 2: gather(P2)+BN+ReLU, @w2b+b2b+ReLU = x2 (regs); pool x2.wl[64:128]
  fused_mlp<0><<<GBF, 256, 0, stream>>>(cnt, bucket, P2, b2a, g2, be2, rm2, rv2,
                                        WT2b, b2b, nullptr, nullptr, bat,
                                        wl + 2 * HID, out);
}

// Round 8
// 309.553 us; speedup vs baseline: 3.7971x; 1.0603x over previous
//
#include <hip/hip_runtime.h>

constexpr int N_NODES  = 50000;
constexpr int N_EDGES  = 400000;
constexpr int N_GRAPHS = 512;
constexpr int IN_DIM   = 768;
constexpr int HID      = 64;
constexpr float BN_EPS = 1e-5f;
constexpr int CAP      = 64;   // max in-degree ~27 (Poisson 8); 64 is bulletproof

typedef __attribute__((ext_vector_type(8))) short bf16x8;
typedef __attribute__((ext_vector_type(4))) float f32x4;

__device__ __forceinline__ float bf2f(ushort u) {
  return __uint_as_float((unsigned int)u << 16);
}
__device__ __forceinline__ ushort f2bf(float f) {  // RNE
  unsigned int u = __float_as_uint(f);
  u = (u + 0x7fff + ((u >> 16) & 1)) >> 16;
  return (ushort)u;
}

// w1a^T -> WT, {w1b,w2a,w2b}^T -> WT*b (bf16), out = bl bcast, cnt = 0
constexpr int W1A_E = HID * IN_DIM;     // 49152
constexpr int WB_E  = HID * HID;        // 4096
__global__ __launch_bounds__(256) void convert_all(
    const float* __restrict__ w1a, const float* __restrict__ w1b,
    const float* __restrict__ w2a, const float* __restrict__ w2b,
    const float* __restrict__ bl,
    ushort* __restrict__ WT, ushort* __restrict__ WT1b,
    ushort* __restrict__ WT2a, ushort* __restrict__ WT2b,
    float* __restrict__ out, int* __restrict__ cnt) {
  int i = blockIdx.x * 256 + threadIdx.x;
  if (i < W1A_E) {
    int c = i / IN_DIM, k = i - c * IN_DIM;
    WT[i] = f2bf(w1a[(size_t)k * HID + c]);
    return;
  }
  int j = i - W1A_E;
  if (j < 3 * WB_E) {
    int w = j / WB_E, r = j - w * WB_E;
    int c = r / HID, k = r - c * HID;
    const float* W = (w == 0) ? w1b : (w == 1) ? w2a : w2b;
    ushort* D = (w == 0) ? WT1b : (w == 1) ? WT2a : WT2b;
    D[r] = f2bf(W[(size_t)k * HID + c]);
    return;
  }
  int o = j - 3 * WB_E;
  if (o < N_GRAPHS * 2) { out[o] = bl[o & 1]; return; }
  int z = o - N_GRAPHS * 2;
  if (z < N_NODES) cnt[z] = 0;
}

constexpr int GB1 = (N_NODES + 127) / 128;   // 391 gemm blocks
constexpr int BB  = (N_EDGES + 255) / 256;   // 1563 build blocks

// Hybrid dispatch: blocks [0,GB1) compute P[n,64] = bf16(X @ w1a) via MFMA
// (128-row tiles); blocks [GB1, GB1+BB) build the dst->src buckets. The
// build's latency-bound atomics hide behind the GEMM's HBM streaming.
__global__ __launch_bounds__(256) void gemm_build(const float* __restrict__ X,
                                                  const ushort* __restrict__ WT,
                                                  ushort* __restrict__ P,
                                                  const int* __restrict__ src,
                                                  const int* __restrict__ dst,
                                                  int* __restrict__ cnt,
                                                  int* __restrict__ bucket) {
  const int tid = threadIdx.x;

  if (blockIdx.x >= GB1) {   // ---- bucket build ----
    int e = (blockIdx.x - GB1) * 256 + tid;
    if (e < N_EDGES) {
      int s = src[e];
      int d = dst[e];
      int slot = atomicAdd(&cnt[d], 1);
      if (slot < CAP) bucket[d * CAP + slot] = s;
    }
    return;
  }

  // ---- GEMM: 128-row tile ----
  __shared__ ushort xs[128][64];   // [row][k], 16B chunks XOR-swizzled by row&7
  __shared__ ushort ws[64][64];    // [col][k]
  const int row0 = blockIdx.x * 128;
  const int wave = tid >> 6, lane = tid & 63, quad = lane >> 4, l16 = lane & 15;

  // X staging: 2 threads/row, 32 k-cols each
  const int srow = tid >> 1;
  const int sk   = (tid & 1) * 32;
  int gr = row0 + srow;
  gr = gr < N_NODES ? gr : N_NODES - 1;
  const float* xrow = &X[(size_t)gr * IN_DIM + sk];
  // WT staging: 4 threads/col, TWO 16B chunks each (8 chunks per 64-elem row)
  const int wrow = tid >> 2;
  const int wc0  = (tid & 3) * 2;
  const ushort* wrp = &WT[(size_t)wrow * IN_DIM + wc0 * 8];

  f32x4 acc[2][4] = {};

  float4 xv[8];
#pragma unroll
  for (int i = 0; i < 8; i++) xv[i] = *(const float4*)&xrow[i * 4];
  uint4 wv0 = *(const uint4*)&wrp[0];
  uint4 wv1 = *(const uint4*)&wrp[8];

  for (int kt = 0; kt < IN_DIM; kt += 64) {
    ushort xb[32];
#pragma unroll
    for (int i = 0; i < 8; i++) {
      xb[i * 4 + 0] = f2bf(xv[i].x);
      xb[i * 4 + 1] = f2bf(xv[i].y);
      xb[i * 4 + 2] = f2bf(xv[i].z);
      xb[i * 4 + 3] = f2bf(xv[i].w);
    }
#pragma unroll
    for (int j = 0; j < 4; j++)
      *(uint4*)&xs[srow][(((sk >> 3) + j) ^ (srow & 7)) * 8] = *(uint4*)&xb[j * 8];
    *(uint4*)&ws[wrow][((wc0 + 0) ^ (wrow & 7)) * 8] = wv0;
    *(uint4*)&ws[wrow][((wc0 + 1) ^ (wrow & 7)) * 8] = wv1;
    __syncthreads();

    if (kt + 64 < IN_DIM) {
#pragma unroll
      for (int i = 0; i < 8; i++) xv[i] = *(const float4*)&xrow[kt + 64 + i * 4];
      wv0 = *(const uint4*)&wrp[kt + 64];
      wv1 = *(const uint4*)&wrp[kt + 64 + 8];
    }

    const int ar0 = wave * 32 + l16;
    const int ar1 = ar0 + 16;
#pragma unroll
    for (int ks = 0; ks < 2; ks++) {
      bf16x8 a0 = *(const bf16x8*)&xs[ar0][((ks * 4 + quad) ^ (ar0 & 7)) * 8];
      bf16x8 a1 = *(const bf16x8*)&xs[ar1][((ks * 4 + quad) ^ (ar1 & 7)) * 8];
#pragma unroll
      for (int ct = 0; ct < 4; ct++) {
        const int br = ct * 16 + l16;
        bf16x8 b = *(const bf16x8*)&ws[br][((ks * 4 + quad) ^ (br & 7)) * 8];
        acc[0][ct] = __builtin_amdgcn_mfma_f32_16x16x32_bf16(a0, b, acc[0][ct], 0, 0, 0);
        acc[1][ct] = __builtin_amdgcn_mfma_f32_16x16x32_bf16(a1, b, acc[1][ct], 0, 0, 0);
      }
    }
    __syncthreads();
  }

#pragma unroll
  for (int g2 = 0; g2 < 2; g2++)
#pragma unroll
    for (int ct = 0; ct < 4; ct++)
#pragma unroll
      for (int r = 0; r < 4; r++) {
        int row = row0 + wave * 32 + g2 * 16 + quad * 4 + r;
        if (row < N_NODES)
          P[(size_t)row * HID + ct * 16 + l16] = f2bf(acc[g2][ct][r]);
      }
}

// Fused GIN layer: gather(Pin)+BN/ReLU staging + MFMA(WT1)+b1+ReLU = xL (regs),
// pool partial: out[batch[n]] += xL[n] . wlh  (LDS gacc -> few global atomics).
// CHAIN: additionally OUT2 = xL_tile @ WT2 (raw) via a 2nd MFMA.
template <int CHAIN>
__global__ __launch_bounds__(256) void fused_mlp(
    const int* __restrict__ cnt, const int* __restrict__ bucket,
    const ushort* __restrict__ Pin,
    const float* __restrict__ bin, const float* __restrict__ g,
    const float* __restrict__ be, const float* __restrict__ rm,
    const float* __restrict__ rv,
    const ushort* __restrict__ WT1, const float* __restrict__ b1,
    const ushort* __restrict__ WT2, ushort* __restrict__ OUT2,
    const int* __restrict__ batch, const float* __restrict__ wlh,
    float* __restrict__ out) {
  __shared__ ushort xs[64][64];             // swizzled A-tile
  __shared__ ushort ws[64][64];             // WT1 [col][k] swizzled
  __shared__ ushort ws2[CHAIN ? 64 : 1][64];// WT2 (CHAIN only)
  __shared__ float sS[64], sT[64];
  __shared__ float gacc[N_GRAPHS * 2];      // 4 KB per-block graph accumulators
  __shared__ float wl_s[2 * HID];           // this layer's half of wl: [64][2]
  const int tid  = threadIdx.x;
  const int row0 = blockIdx.x * 64;
  const int srow = tid >> 2;        // node-in-tile (staging)
  const int sub  = tid & 3;         // 16-col group
  const int qc0  = sub * 2;         // 16B-chunk pair

#pragma unroll
  for (int i = tid; i < N_GRAPHS * 2; i += 256) gacc[i] = 0.0f;
  if (tid < 2 * HID) wl_s[tid] = wlh[tid];
  if (tid < 64) {
    float s = g[tid] * rsqrtf(rv[tid] + BN_EPS);
    sS[tid] = s;
    sT[tid] = (bin[tid] - rm[tid]) * s + be[tid];
  }
  {
    uint4 w0 = *(const uint4*)&WT1[(size_t)srow * HID + qc0 * 8];
    uint4 w1 = *(const uint4*)&WT1[(size_t)srow * HID + qc0 * 8 + 8];
    *(uint4*)&ws[srow][((qc0 + 0) ^ (srow & 7)) * 8] = w0;
    *(uint4*)&ws[srow][((qc0 + 1) ^ (srow & 7)) * 8] = w1;
    if (CHAIN) {
      uint4 v0 = *(const uint4*)&WT2[(size_t)srow * HID + qc0 * 8];
      uint4 v1 = *(const uint4*)&WT2[(size_t)srow * HID + qc0 * 8 + 8];
      *(uint4*)&ws2[srow][((qc0 + 0) ^ (srow & 7)) * 8] = v0;
      *(uint4*)&ws2[srow][((qc0 + 1) ^ (srow & 7)) * 8] = v1;
    }
  }
  __syncthreads();   // sS/sT/gacc/wl_s ready

  // ---- gather + BN + ReLU -> stage h into xs (4 threads/node, fp32 agg) ----
  {
    int node = row0 + srow;
    node = node < N_NODES ? node : N_NODES - 1;
    float acc[16];
    {
      ushort b0[16];
      const ushort* base = &Pin[(size_t)node * HID + sub * 16];
      *(uint4*)&b0[0] = *(const uint4*)&base[0];
      *(uint4*)&b0[8] = *(const uint4*)&base[8];
#pragma unroll
      for (int j = 0; j < 16; j++) acc[j] = bf2f(b0[j]);
    }
    int c = cnt[node];
    c = c < CAP ? c : CAP;
    const int* bkt = &bucket[node * CAP];
    int i = 0;
    for (; i + 4 <= c; i += 4) {
      int4 s4 = *(const int4*)&bkt[i];
      ushort r0[16], r1[16], r2[16], r3[16];
      const ushort* p0 = &Pin[(size_t)s4.x * HID + sub * 16];
      const ushort* p1 = &Pin[(size_t)s4.y * HID + sub * 16];
      const ushort* p2 = &Pin[(size_t)s4.z * HID + sub * 16];
      const ushort* p3 = &Pin[(size_t)s4.w * HID + sub * 16];
      *(uint4*)&r0[0] = *(const uint4*)&p0[0]; *(uint4*)&r0[8] = *(const uint4*)&p0[8];
      *(uint4*)&r1[0] = *(const uint4*)&p1[0]; *(uint4*)&r1[8] = *(const uint4*)&p1[8];
      *(uint4*)&r2[0] = *(const uint4*)&p2[0]; *(uint4*)&r2[8] = *(const uint4*)&p2[8];
      *(uint4*)&r3[0] = *(const uint4*)&p3[0]; *(uint4*)&r3[8] = *(const uint4*)&p3[8];
#pragma unroll
      for (int j = 0; j < 16; j++)
        acc[j] += (bf2f(r0[j]) + bf2f(r1[j])) + (bf2f(r2[j]) + bf2f(r3[j]));
    }
    for (; i < c; i++) {
      const ushort* p0 = &Pin[(size_t)bkt[i] * HID + sub * 16];
      ushort r0[16];
      *(uint4*)&r0[0] = *(const uint4*)&p0[0]; *(uint4*)&r0[8] = *(const uint4*)&p0[8];
#pragma unroll
      for (int j = 0; j < 16; j++) acc[j] += bf2f(r0[j]);
    }
    ushort hb[16];
#pragma unroll
    for (int j = 0; j < 16; j++) {
      int col = sub * 16 + j;
      float v = fmaxf(fmaf(acc[j], sS[col], sT[col]), 0.0f);
      hb[j] = f2bf(v);
    }
    *(uint4*)&xs[srow][((qc0 + 0) ^ (srow & 7)) * 8] = *(uint4*)&hb[0];
    *(uint4*)&xs[srow][((qc0 + 1) ^ (srow & 7)) * 8] = *(uint4*)&hb[8];
  }
  __syncthreads();

  const int wave = tid >> 6, lane = tid & 63, quad = lane >> 4, l16 = lane & 15;
  const int ar = wave * 16 + l16, axor = ar & 7;

  // ---- GEMM 1: h @ W1 ----
  f32x4 acc1[4] = {};
#pragma unroll
  for (int ks = 0; ks < 2; ks++) {
    bf16x8 a = *(const bf16x8*)&xs[ar][((ks * 4 + quad) ^ axor) * 8];
#pragma unroll
    for (int ct = 0; ct < 4; ct++) {
      const int br = ct * 16 + l16;
      bf16x8 b = *(const bf16x8*)&ws[br][((ks * 4 + quad) ^ (br & 7)) * 8];
      acc1[ct] = __builtin_amdgcn_mfma_f32_16x16x32_bf16(a, b, acc1[ct], 0, 0, 0);
    }
  }

  if (CHAIN) __syncthreads();   // all xs reads done before restage overwrite

  // epilogue: xL = relu(acc1 + b1) in fp32 regs (C layout: col=ct*16+l16, row=quad*4+r)
  float v[4][4];
#pragma unroll
  for (int ct = 0; ct < 4; ct++) {
    const float bo = b1[ct * 16 + l16];
#pragma unroll
    for (int r = 0; r < 4; r++) v[ct][r] = fmaxf(acc1[ct][r] + bo, 0.0f);
  }

  // ---- fused pool partial: p[r] = xL[row] . wlh ----
  {
    float p0[4] = {}, p1[4] = {};
#pragma unroll
    for (int ct = 0; ct < 4; ct++) {
      const int col = ct * 16 + l16;
      const float w0 = wl_s[col * 2 + 0], w1 = wl_s[col * 2 + 1];
#pragma unroll
      for (int r = 0; r < 4; r++) {
        p0[r] = fmaf(v[ct][r], w0, p0[r]);
        p1[r] = fmaf(v[ct][r], w1, p1[r]);
      }
    }
#pragma unroll
    for (int m = 1; m < 16; m <<= 1) {
#pragma unroll
      for (int r = 0; r < 4; r++) {
        p0[r] += __shfl_xor(p0[r], m);
        p1[r] += __shfl_xor(p1[r], m);
      }
    }
    if (l16 == 0) {
#pragma unroll
      for (int r = 0; r < 4; r++) {
        int node = row0 + wave * 16 + quad * 4 + r;
        if (node < N_NODES) {
          int gi = batch[node];
          atomicAdd(&gacc[gi * 2 + 0], p0[r]);
          atomicAdd(&gacc[gi * 2 + 1], p1[r]);
        }
      }
    }
  }

  if (CHAIN) {
    // restage bf16(xL) into xs, then GEMM 2: xL @ W2 -> OUT2 (raw projection)
#pragma unroll
    for (int ct = 0; ct < 4; ct++) {
      const int col = ct * 16 + l16;
#pragma unroll
      for (int r = 0; r < 4; r++) {
        int lrow = wave * 16 + quad * 4 + r;
        xs[lrow][(((col >> 3) ^ (lrow & 7)) * 8) + (col & 7)] = f2bf(v[ct][r]);
      }
    }
    __syncthreads();

    f32x4 acc2[4] = {};
#pragma unroll
    for (int ks = 0; ks < 2; ks++) {
      bf16x8 a = *(const bf16x8*)&xs[ar][((ks * 4 + quad) ^ axor) * 8];
#pragma unroll
      for (int ct = 0; ct < 4; ct++) {
        const int br = ct * 16 + l16;
        bf16x8 b = *(const bf16x8*)&ws2[br][((ks * 4 + quad) ^ (br & 7)) * 8];
        acc2[ct] = __builtin_amdgcn_mfma_f32_16x16x32_bf16(a, b, acc2[ct], 0, 0, 0);
      }
    }
#pragma unroll
    for (int ct = 0; ct < 4; ct++) {
      const int col = ct * 16 + l16;
#pragma unroll
      for (int r = 0; r < 4; r++) {
        int grow = row0 + wave * 16 + quad * 4 + r;
        if (grow < N_NODES) OUT2[(size_t)grow * HID + col] = f2bf(acc2[ct][r]);
      }
    }
  }

  // ---- flush per-block graph partials (few nonzero: batch is sorted) ----
  __syncthreads();
#pragma unroll
  for (int i = tid; i < N_GRAPHS * 2; i += 256) {
    float vv = gacc[i];
    if (vv != 0.0f) atomicAdd(&out[i], vv);
  }
}

extern "C" void kernel_launch(void* const* d_in, const int* in_sizes, int n_in,
                              void* d_out, int out_size, void* d_ws, size_t ws_size,
                              hipStream_t stream) {
  const float* x   = (const float*)d_in[0];
  const int*   ei  = (const int*)d_in[1];
  const int*   bat = (const int*)d_in[2];
  const float* w1a = (const float*)d_in[3];
  const float* b1a = (const float*)d_in[4];
  const float* g1  = (const float*)d_in[5];
  const float* be1 = (const float*)d_in[6];
  const float* rm1 = (const float*)d_in[7];
  const float* rv1 = (const float*)d_in[8];
  const float* w1b = (const float*)d_in[9];
  const float* b1b = (const float*)d_in[10];
  const float* w2a = (const float*)d_in[11];
  const float* b2a = (const float*)d_in[12];
  const float* g2  = (const float*)d_in[13];
  const float* be2 = (const float*)d_in[14];
  const float* rm2 = (const float*)d_in[15];
  const float* rv2 = (const float*)d_in[16];
  const float* w2b = (const float*)d_in[17];
  const float* b2b = (const float*)d_in[18];
  const float* wl  = (const float*)d_in[19];
  const float* bl  = (const float*)d_in[20];
  float* out = (float*)d_out;

  const int* src = ei;
  const int* dst = ei + N_EDGES;

  const size_t FB = (size_t)N_NODES * HID;
  ushort* P1   = (ushort*)d_ws;              // 6.4 MB
  ushort* P2   = P1 + FB;                    // 6.4 MB
  ushort* WT   = P2 + FB;                    // 96 KB (w1a^T)
  ushort* WT1b = WT + (size_t)W1A_E;         // 8 KB each
  ushort* WT2a = WT1b + WB_E;
  ushort* WT2b = WT2a + WB_E;
  int* cnt     = (int*)(WT2b + WB_E);        // 200 KB
  int* bucket  = cnt + N_NODES;              // 12.8 MB  (total ~26 MB)

  const int GBF = (N_NODES + 63) / 64;       // 782 (fused layers)
  const int CB  = (W1A_E + 3 * WB_E + N_GRAPHS * 2 + N_NODES + 255) / 256;

  // weights->bf16^T, out=bl, cnt=0
  convert_all<<<CB, 256, 0, stream>>>(w1a, w1b, w2a, w2b, bl,
                                      WT, WT1b, WT2a, WT2b, out, cnt);
  // Hybrid: P1 = x @ w1a (MFMA) + bucket build (overlapped, independent)
  gemm_build<<<GB1 + BB, 256, 0, stream>>>(x, WT, P1, src, dst, cnt, bucket);
  // Layer 1: gather(P1)+BN+ReLU, @w1b+b1b+ReLU = x1 (regs); pool x1.wl[0:64];
  //          chain P2 = x1 @ w2a
  fused_mlp<1><<<GBF, 256, 0, stream>>>(cnt, bucket, P1, b1a, g1, be1, rm1, rv1,
                                        WT1b, b1b, WT2a, P2, bat, wl, out);
  // Layer 2: gather(P2)+BN+ReLU, @w2b+b2b+ReLU = x2 (regs); pool x2.wl[64:128]
  fused_mlp<0><<<GBF, 256, 0, stream>>>(cnt, bucket, P2, b2a, g2, be2, rm2, rv2,
                                        WT2b, b2b, nullptr, nullptr, bat,
                                        wl + 2 * HID, out);
}